// Round 5
// baseline (835.777 us; speedup 1.0000x reference)
//
#include <hip/hip_runtime.h>
#include <math.h>

typedef unsigned short u16;
typedef __bf16 bf16t;
typedef bf16t bf16x8 __attribute__((ext_vector_type(8)));
typedef u16 u16x8 __attribute__((ext_vector_type(8)));
typedef float f32x4 __attribute__((ext_vector_type(4)));

#define D_ 1024
#define S_ 4096
#define B_ 4
#define NB 16
#define BS 256
#define NH 16
#define HD 64

__device__ __forceinline__ float bfu2f(u16 u) {
  unsigned int x = ((unsigned int)u) << 16;
  float f; __builtin_memcpy(&f, &x, 4); return f;
}
__device__ __forceinline__ u16 f2bfu(float f) {
  unsigned int x; __builtin_memcpy(&x, &f, 4);
  x += 0x7fffu + ((x >> 16) & 1u);   // RNE
  return (u16)(x >> 16);
}
__device__ __forceinline__ bf16x8 u2b16(u16x8 u) {
  bf16x8 r; __builtin_memcpy(&r, &u, 16); return r;
}
__device__ __forceinline__ void gld_lds16(const void* g, void* l) {
  __builtin_amdgcn_global_load_lds((__attribute__((address_space(1))) void*)g,
                                   (__attribute__((address_space(3))) void*)l, 16, 0, 0);
}

// ---------------- block means, two-stage ----------------
__global__ __launch_bounds__(256) void mean1_kernel(const float* __restrict__ x,
                                                    float* __restrict__ xbp) {
  int bx = blockIdx.x;
  int o = bx >> 3, p = bx & 7;
  int b = o >> 4, n = o & 15;
  int t = threadIdx.x;
  float4 acc = {0.f, 0.f, 0.f, 0.f};
  const float* xp = x + ((long)(n * BS + p * 32) * B_ + b) * D_ + t * 4;
  for (int s = 0; s < 32; ++s) {
    float4 u = *(const float4*)xp;
    acc.x += u.x; acc.y += u.y; acc.z += u.z; acc.w += u.w;
    xp += B_ * D_;
  }
  *(float4*)(xbp + (long)bx * D_ + t * 4) = acc;
}
__global__ __launch_bounds__(256) void mean2_kernel(const float* __restrict__ xbp,
                                                    float* __restrict__ xb) {
  int o = blockIdx.x, t = threadIdx.x;
  float4 acc = {0.f, 0.f, 0.f, 0.f};
#pragma unroll
  for (int p = 0; p < 8; ++p) {
    float4 u = *(const float4*)(xbp + (long)(o * 8 + p) * D_ + t * 4);
    acc.x += u.x; acc.y += u.y; acc.z += u.z; acc.w += u.w;
  }
  float4 r = {acc.x * (1.f / BS), acc.y * (1.f / BS), acc.z * (1.f / BS), acc.w * (1.f / BS)};
  *(float4*)(xb + (long)o * D_ + t * 4) = r;
}

// ---------------- q_blk / k_blk ----------------
__global__ __launch_bounds__(256) void qkblk2_kernel(const float* __restrict__ xb,
    const float* __restrict__ Wq, const float* __restrict__ bq,
    const float* __restrict__ Wk, const float* __restrict__ bk,
    float* __restrict__ qb, float* __restrict__ kb) {
  int m = blockIdx.x >> 5, ct = blockIdx.x & 31;
  const float* W  = m ? Wk : Wq;
  const float* bi = m ? bk : bq;
  float* out      = m ? kb : qb;
  __shared__ float As[64][132];
  __shared__ float Ws[32][132];
  int t = threadIdx.x;
  int col = t & 31, rg = t >> 5;
  float acc[8];
#pragma unroll
  for (int i = 0; i < 8; ++i) acc[i] = 0.f;
  int srow = t >> 2, sks = (t & 3) * 32;
  for (int kc = 0; kc < 8; ++kc) {
    int k0 = kc * 128;
    __syncthreads();
#pragma unroll
    for (int j = 0; j < 8; ++j)
      *(float4*)&As[srow][sks + j * 4] = *(const float4*)(xb + (long)srow * D_ + k0 + sks + j * 4);
    if (t < 128) {
      int c = t >> 2, ks = (t & 3) * 32;
#pragma unroll
      for (int j = 0; j < 8; ++j)
        *(float4*)&Ws[c][ks + j * 4] =
            *(const float4*)(W + (long)(ct * 32 + c) * D_ + k0 + ks + j * 4);
    }
    __syncthreads();
#pragma unroll
    for (int k4 = 0; k4 < 32; ++k4) {
      float4 wv = *(const float4*)&Ws[col][k4 * 4];
#pragma unroll
      for (int i = 0; i < 8; ++i) {
        float4 av = *(const float4*)&As[rg * 8 + i][k4 * 4];
        acc[i] += av.x * wv.x + av.y * wv.y + av.z * wv.z + av.w * wv.w;
      }
    }
  }
  float bv = bi[ct * 32 + col];
#pragma unroll
  for (int i = 0; i < 8; ++i)
    out[(long)(rg * 8 + i) * D_ + ct * 32 + col] = acc[i] + bv;
}

// ---------------- logits ----------------
__global__ __launch_bounds__(256) void logits_kernel(const float* __restrict__ qb,
                                                     const float* __restrict__ kb,
                                                     float* __restrict__ lg) {
  int idx = blockIdx.x * 4 + (threadIdx.x >> 6);
  int b = idx >> 8, n = (idx >> 4) & 15, m = idx & 15;
  int lane = threadIdx.x & 63;
  float acc = 0.f;
  const float* qp = qb + (b * 16 + n) * D_ + lane;
  const float* kp = kb + (b * 16 + m) * D_ + lane;
#pragma unroll
  for (int kk = 0; kk < 16; ++kk) acc += qp[kk * 64] * kp[kk * 64];
#pragma unroll
  for (int mm = 1; mm < 64; mm <<= 1) acc += __shfl_xor(acc, mm);
  if (lane == 0) lg[idx] = acc * (1.f / 32.f);
}

// ---------------- Sinkhorn + argmax ----------------
__global__ __launch_bounds__(256) void sinkhorn_kernel(const float* __restrict__ lg,
                                                       int* __restrict__ perm) {
  int b = blockIdx.x;
  __shared__ float L[16][17];
  int t = threadIdx.x;
  int n = t >> 4, m = t & 15;
  L[n][m] = lg[b * 256 + t];
  __syncthreads();
  for (int it = 0; it < 5; ++it) {
    float mx = -3e38f;
#pragma unroll
    for (int i = 0; i < 16; ++i) mx = fmaxf(mx, L[n][i]);
    float sm = 0.f;
#pragma unroll
    for (int i = 0; i < 16; ++i) sm += expf(L[n][i] - mx);
    float lse = mx + logf(sm);
    __syncthreads();
    L[n][m] -= lse;
    __syncthreads();
    mx = -3e38f;
#pragma unroll
    for (int i = 0; i < 16; ++i) mx = fmaxf(mx, L[i][m]);
    sm = 0.f;
#pragma unroll
    for (int i = 0; i < 16; ++i) sm += expf(L[i][m] - mx);
    lse = mx + logf(sm);
    __syncthreads();
    L[n][m] -= lse;
    __syncthreads();
  }
  if (t < 16) {
    float best = -3e38f; int bi = 0;
#pragma unroll
    for (int i = 0; i < 16; ++i) {
      float v = L[t][i];
      if (v > best) { best = v; bi = i; }
    }
    perm[b * 16 + t] = bi;
  }
}

// ---------------- merged weight split: 4 matrices -> hi/lo bf16 ----------------
__global__ __launch_bounds__(256) void wsplit_kernel(
    const float* __restrict__ Wq, const float* __restrict__ Wk,
    const float* __restrict__ Wv, const float* __restrict__ Wo,
    u16* __restrict__ whi, u16* __restrict__ wlo,
    u16* __restrict__ wohi, u16* __restrict__ wolo) {
  const size_t NW = (size_t)D_ * D_;
  int z = blockIdx.y;
  const float* src = (z == 0) ? Wq : (z == 1) ? Wk : (z == 2) ? Wv : Wo;
  u16* dh = (z < 3) ? (whi + (size_t)z * NW) : wohi;
  u16* dl = (z < 3) ? (wlo + (size_t)z * NW) : wolo;
  long i = (long)blockIdx.x * 256 + threadIdx.x;
  float4 v = ((const float4*)src)[i];
  ushort4 h, l;
  h.x = f2bfu(v.x); l.x = f2bfu(v.x - bfu2f(h.x));
  h.y = f2bfu(v.y); l.y = f2bfu(v.y - bfu2f(h.y));
  h.z = f2bfu(v.z); l.z = f2bfu(v.z - bfu2f(h.z));
  h.w = f2bfu(v.w); l.w = f2bfu(v.w - bfu2f(h.w));
  ((ushort4*)dh)[i] = h;
  ((ushort4*)dl)[i] = l;
}

// ---------------- x split: (S,B,D) fp32 -> hi/lo bf16, once ----------------
__global__ __launch_bounds__(256) void xsplit_kernel(const float* __restrict__ x,
    u16* __restrict__ xhi, u16* __restrict__ xlo) {
  long i = (long)blockIdx.x * 256 + threadIdx.x;
  float4 v = ((const float4*)x)[i];
  ushort4 h, l;
  h.x = f2bfu(v.x); l.x = f2bfu(v.x - bfu2f(h.x));
  h.y = f2bfu(v.y); l.y = f2bfu(v.y - bfu2f(h.y));
  h.z = f2bfu(v.z); l.z = f2bfu(v.z - bfu2f(h.z));
  h.w = f2bfu(v.w); l.w = f2bfu(v.w - bfu2f(h.w));
  ((ushort4*)xhi)[i] = h;
  ((ushort4*)xlo)[i] = l;
}

// ---------------- QKV GEMM v4: 2-phase double-buffered staging ----------------
// Per k-step: STAGE(next tile) -> ds_read(cur) -> MFMA -> one __syncthreads().
// Staging latency hides under the MFMA cluster (T3 minimum-2-phase recipe).
// Swizzle unchanged from v3 (bank-conflict-free, verified 0 conflicts).
__global__ __launch_bounds__(256, 2) void gemm_qkv_kernel(
    const u16* __restrict__ xhi, const u16* __restrict__ xlo,
    const u16* __restrict__ whi, const u16* __restrict__ wlo,
    const float* __restrict__ bq, const float* __restrict__ bk, const float* __restrict__ bv,
    u16* __restrict__ Qbf, u16* __restrict__ Khi, u16* __restrict__ Klo,
    u16* __restrict__ Vbf, const int* __restrict__ perm, int grp) {
  int z = blockIdx.z;
  const u16* Wh = whi + (size_t)z * (D_ * D_);
  const u16* Wl = wlo + (size_t)z * (D_ * D_);
  const float* bi = (z == 0) ? bq : (z == 1) ? bk : bv;
  int g = blockIdx.y >> 5, st = blockIdx.y & 31;
  int b = grp * 2 + g;
  int col0 = blockIdx.x * 128;
  int n = st >> 1;
  int sb = perm[b * NB + n];
  const long a_stride = (long)B_ * D_;
  long a_off = ((long)(sb * BS + (st & 1) * 128) * B_ + b) * D_;
  const u16* Ahg = xhi + a_off;
  const u16* Alg = xlo + a_off;

  __shared__ __attribute__((aligned(16))) u16 Ash[2][4096], Asl[2][4096],
                                              Bsh[2][4096], Bsl[2][4096];
  int t = threadIdx.x;
  int w = t >> 6, lane = t & 63, quad = lane >> 4, l15 = lane & 15;
  int wm = w >> 1, wn = w & 1;
  f32x4 acc[4][4];
#pragma unroll
  for (int i = 0; i < 4; ++i)
#pragma unroll
    for (int j = 0; j < 4; ++j) acc[i][j] = {0.f, 0.f, 0.f, 0.f};

  // staging: 512 chunks of 16B per buffer; chunk ch -> row ch>>2, phys kchunk ch&3,
  // global kchunk = (ch&3) ^ ((ch>>3)&3)
  int ch0 = t, ch1 = t + 256;
  int r0 = ch0 >> 2, kc0 = ((ch0 & 3) ^ ((ch0 >> 3) & 3)) * 8;
  int r1 = ch1 >> 2, kc1 = ((ch1 & 3) ^ ((ch1 >> 3) & 3)) * 8;
  int cswz = (quad ^ ((l15 >> 1) & 3)) * 8;

#define QKV_STAGE(BUF, K0)                                                     \
  do {                                                                         \
    gld_lds16(Ahg + (long)r0 * a_stride + (K0) + kc0, &Ash[BUF][ch0 * 8]);     \
    gld_lds16(Ahg + (long)r1 * a_stride + (K0) + kc1, &Ash[BUF][ch1 * 8]);     \
    gld_lds16(Alg + (long)r0 * a_stride + (K0) + kc0, &Asl[BUF][ch0 * 8]);     \
    gld_lds16(Alg + (long)r1 * a_stride + (K0) + kc1, &Asl[BUF][ch1 * 8]);     \
    gld_lds16(Wh + (long)(col0 + r0) * D_ + (K0) + kc0, &Bsh[BUF][ch0 * 8]);   \
    gld_lds16(Wh + (long)(col0 + r1) * D_ + (K0) + kc1, &Bsh[BUF][ch1 * 8]);   \
    gld_lds16(Wl + (long)(col0 + r0) * D_ + (K0) + kc0, &Bsl[BUF][ch0 * 8]);   \
    gld_lds16(Wl + (long)(col0 + r1) * D_ + (K0) + kc1, &Bsl[BUF][ch1 * 8]);   \
  } while (0)

#define QKV_COMPUTE(BUF)                                                        \
  do {                                                                          \
    bf16x8 ah[4], al[4], bh[4], bl[4];                                          \
    _Pragma("unroll") for (int i = 0; i < 4; ++i) {                             \
      ah[i] = *(const bf16x8*)(&Ash[BUF][0] + (wm * 64 + i * 16 + l15) * 32 + cswz); \
      al[i] = *(const bf16x8*)(&Asl[BUF][0] + (wm * 64 + i * 16 + l15) * 32 + cswz); \
    }                                                                           \
    _Pragma("unroll") for (int j = 0; j < 4; ++j) {                             \
      bh[j] = *(const bf16x8*)(&Bsh[BUF][0] + (wn * 64 + j * 16 + l15) * 32 + cswz); \
      bl[j] = *(const bf16x8*)(&Bsl[BUF][0] + (wn * 64 + j * 16 + l15) * 32 + cswz); \
    }                                                                           \
    _Pragma("unroll") for (int i = 0; i < 4; ++i)                               \
      _Pragma("unroll") for (int j = 0; j < 4; ++j) {                           \
        acc[i][j] = __builtin_amdgcn_mfma_f32_16x16x32_bf16(al[i], bh[j], acc[i][j], 0, 0, 0); \
        acc[i][j] = __builtin_amdgcn_mfma_f32_16x16x32_bf16(ah[i], bl[j], acc[i][j], 0, 0, 0); \
        acc[i][j] = __builtin_amdgcn_mfma_f32_16x16x32_bf16(ah[i], bh[j], acc[i][j], 0, 0, 0); \
      }                                                                         \
  } while (0)

  QKV_STAGE(0, 0);
  __syncthreads();
  int cur = 0;
#pragma unroll 1
  for (int kt = 0; kt < 31; ++kt) {
    QKV_STAGE(cur ^ 1, (kt + 1) * 32);
    QKV_COMPUTE(cur);
    __syncthreads();
    cur ^= 1;
  }
  QKV_COMPUTE(cur);
#undef QKV_STAGE
#undef QKV_COMPUTE

#pragma unroll
  for (int j = 0; j < 4; ++j) {
    float bvv = bi[col0 + wn * 64 + j * 16 + l15];
#pragma unroll
    for (int i = 0; i < 4; ++i) {
      int row = wm * 64 + i * 16 + quad * 4;
      long base = ((long)g * S_ + st * 128 + row) * D_ + col0 + wn * 64 + j * 16 + l15;
#pragma unroll
      for (int r = 0; r < 4; ++r) {
        float val = acc[i][j][r] + bvv;
        long a = base + (long)r * D_;
        if (z == 0) {
          Qbf[a] = f2bfu(val * 0.125f);
        } else if (z == 1) {
          u16 hh = f2bfu(val);
          Khi[a] = hh;
          Klo[a] = f2bfu(val - bfu2f(hh));
        } else {
          Vbf[a] = f2bfu(val);
        }
      }
    }
  }
}

// ---------------- out GEMM: 2-phase double-buffered variant ----------------
__global__ __launch_bounds__(256, 2) void gemm_out_kernel(
    const u16* __restrict__ Ahi, const u16* __restrict__ Alo,
    const u16* __restrict__ wohi, const u16* __restrict__ wolo,
    const float* __restrict__ bo, float* __restrict__ out, int grp) {
  int g = blockIdx.y >> 5, st = blockIdx.y & 31;
  int b = grp * 2 + g;
  int col0 = blockIdx.x * 128;
  long a_off = ((long)g * S_ + st * 128) * D_;
  const u16* Ah = Ahi + a_off;
  const u16* Al = Alo + a_off;
  float* cbase = out + ((long)(st * 128) * B_ + b) * D_;
  const long c_stride = (long)B_ * D_;

  __shared__ __attribute__((aligned(16))) u16 Ash[2][4096], Asl[2][4096],
                                              Bsh[2][4096], Bsl[2][4096];
  int t = threadIdx.x;
  int w = t >> 6, lane = t & 63, quad = lane >> 4, l15 = lane & 15;
  int wm = w >> 1, wn = w & 1;
  f32x4 acc[4][4];
#pragma unroll
  for (int i = 0; i < 4; ++i)
#pragma unroll
    for (int j = 0; j < 4; ++j) acc[i][j] = {0.f, 0.f, 0.f, 0.f};

  int ch0 = t, ch1 = t + 256;
  int r0 = ch0 >> 2, kc0 = ((ch0 & 3) ^ ((ch0 >> 3) & 3)) * 8;
  int r1 = ch1 >> 2, kc1 = ((ch1 & 3) ^ ((ch1 >> 3) & 3)) * 8;
  int cswz = (quad ^ ((l15 >> 1) & 3)) * 8;

#define OUT_STAGE(BUF, K0)                                                      \
  do {                                                                          \
    gld_lds16(Ah + (long)r0 * D_ + (K0) + kc0, &Ash[BUF][ch0 * 8]);             \
    gld_lds16(Ah + (long)r1 * D_ + (K0) + kc1, &Ash[BUF][ch1 * 8]);             \
    gld_lds16(Al + (long)r0 * D_ + (K0) + kc0, &Asl[BUF][ch0 * 8]);             \
    gld_lds16(Al + (long)r1 * D_ + (K0) + kc1, &Asl[BUF][ch1 * 8]);             \
    gld_lds16(wohi + (long)(col0 + r0) * D_ + (K0) + kc0, &Bsh[BUF][ch0 * 8]);  \
    gld_lds16(wohi + (long)(col0 + r1) * D_ + (K0) + kc1, &Bsh[BUF][ch1 * 8]);  \
    gld_lds16(wolo + (long)(col0 + r0) * D_ + (K0) + kc0, &Bsl[BUF][ch0 * 8]);  \
    gld_lds16(wolo + (long)(col0 + r1) * D_ + (K0) + kc1, &Bsl[BUF][ch1 * 8]);  \
  } while (0)

#define OUT_COMPUTE(BUF)                                                        \
  do {                                                                          \
    bf16x8 ah[4], al[4], bh[4], bl[4];                                          \
    _Pragma("unroll") for (int i = 0; i < 4; ++i) {                             \
      ah[i] = *(const bf16x8*)(&Ash[BUF][0] + (wm * 64 + i * 16 + l15) * 32 + cswz); \
      al[i] = *(const bf16x8*)(&Asl[BUF][0] + (wm * 64 + i * 16 + l15) * 32 + cswz); \
    }                                                                           \
    _Pragma("unroll") for (int j = 0; j < 4; ++j) {                             \
      bh[j] = *(const bf16x8*)(&Bsh[BUF][0] + (wn * 64 + j * 16 + l15) * 32 + cswz); \
      bl[j] = *(const bf16x8*)(&Bsl[BUF][0] + (wn * 64 + j * 16 + l15) * 32 + cswz); \
    }                                                                           \
    _Pragma("unroll") for (int i = 0; i < 4; ++i)                               \
      _Pragma("unroll") for (int j = 0; j < 4; ++j) {                           \
        acc[i][j] = __builtin_amdgcn_mfma_f32_16x16x32_bf16(al[i], bh[j], acc[i][j], 0, 0, 0); \
        acc[i][j] = __builtin_amdgcn_mfma_f32_16x16x32_bf16(ah[i], bl[j], acc[i][j], 0, 0, 0); \
        acc[i][j] = __builtin_amdgcn_mfma_f32_16x16x32_bf16(ah[i], bh[j], acc[i][j], 0, 0, 0); \
      }                                                                         \
  } while (0)

  OUT_STAGE(0, 0);
  __syncthreads();
  int cur = 0;
#pragma unroll 1
  for (int kt = 0; kt < 31; ++kt) {
    OUT_STAGE(cur ^ 1, (kt + 1) * 32);
    OUT_COMPUTE(cur);
    __syncthreads();
    cur ^= 1;
  }
  OUT_COMPUTE(cur);
#undef OUT_STAGE
#undef OUT_COMPUTE

#pragma unroll
  for (int j = 0; j < 4; ++j) {
    float bvv = bo[col0 + wn * 64 + j * 16 + l15];
#pragma unroll
    for (int i = 0; i < 4; ++i) {
      int row = wm * 64 + i * 16 + quad * 4;
      long base = (long)row * c_stride + col0 + wn * 64 + j * 16 + l15;
#pragma unroll
      for (int r = 0; r < 4; ++r)
        cbase[base + (long)r * c_stride] = acc[i][j][r] + bvv;
    }
  }
}

// ---------------- block-local attention, MFMA flash, bf16 inputs ----------------
// Inputs already bf16: Qbf pre-scaled, Khi/Klo split, Vbf. No conversion VALU.
// aohi aliases Vbf, aolo aliases Qbf (per-workgroup regions disjoint; all reads of a
// region complete before its epilogue write).
__global__ __launch_bounds__(256, 2) void attn_mfma_kernel(
    const u16* __restrict__ Qbf, const u16* __restrict__ KhiG, const u16* __restrict__ KloG,
    const u16* __restrict__ Vbf, u16* __restrict__ aohi, u16* __restrict__ aolo) {
  int g = blockIdx.x >> 8;
  int n = (blockIdx.x >> 4) & 15, h = blockIdx.x & 15;
  long rbase = (long)g * S_ + n * BS;
  int t = threadIdx.x;
  int w = t >> 6, lane = t & 63, quad = lane >> 4, l15 = lane & 15;

  __shared__ __attribute__((aligned(16))) u16 Khi[64][72];
  __shared__ __attribute__((aligned(16))) u16 Klo[64][72];
  __shared__ __attribute__((aligned(16))) u16 Vt[64][72];   // transposed: [d][key]
  __shared__ __attribute__((aligned(16))) u16 Pw[4][64][72];

  bf16x8 vones;
  {
    u16x8 uo;
#pragma unroll
    for (int e = 0; e < 8; ++e) uo[e] = 0x3F80u;  // bf16 1.0
    vones = u2b16(uo);
  }

  // Q fragments: direct bf16 load (pre-scaled by 0.125 in gemm_qkv)
  bf16x8 qf[4][2];
#pragma unroll
  for (int i = 0; i < 4; ++i)
#pragma unroll
    for (int ks = 0; ks < 2; ++ks)
      qf[i][ks] = u2b16(*(const u16x8*)(Qbf +
          (rbase + w * 64 + i * 16 + l15) * (long)D_ + h * HD + ks * 32 + quad * 8));

  f32x4 acc[4][4];
  f32x4 accl[4];
  float m[4][4];
#pragma unroll
  for (int i = 0; i < 4; ++i) {
    accl[i] = {0.f, 0.f, 0.f, 0.f};
#pragma unroll
    for (int j = 0; j < 4; ++j) {
      acc[i][j] = {0.f, 0.f, 0.f, 0.f};
      m[i][j] = -3e38f;
    }
  }

  int skey = t >> 2, sd0 = (t & 3) * 16;

#pragma unroll 1
  for (int c = 0; c < 4; ++c) {
    __syncthreads();
    // ---- stage K hi/lo (copy) and V^T (scatter) ----
    {
      long roff = (rbase + c * 64 + skey) * (long)D_ + h * HD + sd0;
      u16x8 h0 = *(const u16x8*)(KhiG + roff);
      u16x8 h1 = *(const u16x8*)(KhiG + roff + 8);
      u16x8 l0 = *(const u16x8*)(KloG + roff);
      u16x8 l1 = *(const u16x8*)(KloG + roff + 8);
      *(u16x8*)&Khi[skey][sd0] = h0;
      *(u16x8*)&Khi[skey][sd0 + 8] = h1;
      *(u16x8*)&Klo[skey][sd0] = l0;
      *(u16x8*)&Klo[skey][sd0 + 8] = l1;
      u16x8 v0 = *(const u16x8*)(Vbf + roff);
      u16x8 v1 = *(const u16x8*)(Vbf + roff + 8);
#pragma unroll
      for (int e = 0; e < 8; ++e) {
        Vt[sd0 + e][skey] = v0[e];
        Vt[sd0 + 8 + e][skey] = v1[e];
      }
    }
    __syncthreads();

    // ---- S = Q K^T (2-term) ----
    f32x4 s[4][4];
#pragma unroll
    for (int i = 0; i < 4; ++i)
#pragma unroll
      for (int j = 0; j < 4; ++j) s[i][j] = {0.f, 0.f, 0.f, 0.f};
#pragma unroll
    for (int ks = 0; ks < 2; ++ks)
#pragma unroll
      for (int j = 0; j < 4; ++j) {
        bf16x8 kh = *(const bf16x8*)&Khi[j * 16 + l15][ks * 32 + quad * 8];
        bf16x8 kl = *(const bf16x8*)&Klo[j * 16 + l15][ks * 32 + quad * 8];
#pragma unroll
        for (int i = 0; i < 4; ++i) {
          s[i][j] = __builtin_amdgcn_mfma_f32_16x16x32_bf16(qf[i][ks], kl, s[i][j], 0, 0, 0);
          s[i][j] = __builtin_amdgcn_mfma_f32_16x16x32_bf16(qf[i][ks], kh, s[i][j], 0, 0, 0);
        }
      }

    // ---- online softmax; P -> LDS (bf16) ----
#pragma unroll
    for (int i = 0; i < 4; ++i)
#pragma unroll
      for (int r = 0; r < 4; ++r) {
        float mc = fmaxf(fmaxf(s[i][0][r], s[i][1][r]), fmaxf(s[i][2][r], s[i][3][r]));
#pragma unroll
        for (int mk = 1; mk < 16; mk <<= 1) mc = fmaxf(mc, __shfl_xor(mc, mk));
        float mn = fmaxf(m[i][r], mc);
        float sc = __expf(m[i][r] - mn);
        m[i][r] = mn;
#pragma unroll
        for (int j = 0; j < 4; ++j) {
          float p = __expf(s[i][j][r] - mn);
          Pw[w][i * 16 + quad * 4 + r][j * 16 + l15] = f2bfu(p);
        }
        accl[i][r] *= sc;
#pragma unroll
        for (int jd = 0; jd < 4; ++jd) acc[i][jd][r] *= sc;
      }
    __syncthreads();

    // ---- O += P V ; denom += P * ones ----
#pragma unroll
    for (int ks = 0; ks < 2; ++ks) {
      bf16x8 pa[4], vb[4];
#pragma unroll
      for (int i = 0; i < 4; ++i)
        pa[i] = *(const bf16x8*)&Pw[w][i * 16 + l15][ks * 32 + quad * 8];
#pragma unroll
      for (int jd = 0; jd < 4; ++jd)
        vb[jd] = *(const bf16x8*)&Vt[jd * 16 + l15][ks * 32 + quad * 8];
#pragma unroll
      for (int i = 0; i < 4; ++i) {
#pragma unroll
        for (int jd = 0; jd < 4; ++jd)
          acc[i][jd] = __builtin_amdgcn_mfma_f32_16x16x32_bf16(pa[i], vb[jd], acc[i][jd], 0, 0, 0);
        accl[i] = __builtin_amdgcn_mfma_f32_16x16x32_bf16(pa[i], vones, accl[i], 0, 0, 0);
      }
    }
  }

  // ---- epilogue: normalize, split hi/lo, store ----
#pragma unroll
  for (int i = 0; i < 4; ++i) {
    float il[4];
#pragma unroll
    for (int r = 0; r < 4; ++r) il[r] = 1.f / accl[i][r];
#pragma unroll
    for (int jd = 0; jd < 4; ++jd)
#pragma unroll
      for (int r = 0; r < 4; ++r) {
        float f = acc[i][jd][r] * il[r];
        u16 hh = f2bfu(f);
        u16 ll = f2bfu(f - bfu2f(hh));
        long addr = (rbase + w * 64 + i * 16 + quad * 4 + r) * (long)D_ + h * HD + jd * 16 + l15;
        aohi[addr] = hh;
        aolo[addr] = ll;
      }
  }
}

// ================= Tier C fallback (proven fp32 path) =================
__global__ __launch_bounds__(256, 2) void gemm_f32_kernel(
    const float* __restrict__ A0,
    const float* __restrict__ W0, const float* __restrict__ W1, const float* __restrict__ W2,
    const float* __restrict__ bi0, const float* __restrict__ bi1, const float* __restrict__ bi2,
    float* __restrict__ O0, float* __restrict__ O1, float* __restrict__ O2,
    const int* __restrict__ perm, int b, int mode) {
  int z = blockIdx.z;
  const float* W  = (z == 0) ? W0 : (z == 1 ? W1 : W2);
  const float* bi = (z == 0) ? bi0 : (z == 1 ? bi1 : bi2);
  float* C        = (z == 0) ? O0 : (z == 1 ? O1 : O2);
  int st = blockIdx.y;
  int col0 = blockIdx.x * 128;
  const float* abase; float* cbase; long a_stride, c_stride;
  if (mode == 0) {
    int n = st >> 1;
    int sb = perm[b * NB + n];
    long a_row0 = (long)sb * BS + (st & 1) * 128;
    abase = A0 + (a_row0 * B_ + b) * D_;
    a_stride = (long)B_ * D_;
    cbase = C + (long)(st * 128) * D_;
    c_stride = D_;
  } else {
    abase = A0 + (long)(st * 128) * D_;
    a_stride = D_;
    cbase = C + ((long)(st * 128) * B_ + b) * D_;
    c_stride = (long)B_ * D_;
  }
  __shared__ float As[16][132];
  __shared__ float Bs[16][132];
  int t = threadIdx.x;
  int lr = t >> 1, kq = (t & 1) * 8;
  int m0 = (t >> 4) * 8, n0 = (t & 15) * 8;
  const float* aptr = abase + (long)lr * a_stride + kq;
  const float* bptr = W + (long)(col0 + lr) * D_ + kq;
  float acc[8][8];
#pragma unroll
  for (int i = 0; i < 8; ++i)
#pragma unroll
    for (int j = 0; j < 8; ++j) acc[i][j] = 0.f;
  for (int kt = 0; kt < D_ / 16; ++kt) {
    float4 av0 = *(const float4*)(aptr);
    float4 av1 = *(const float4*)(aptr + 4);
    float4 bv0 = *(const float4*)(bptr);
    float4 bv1 = *(const float4*)(bptr + 4);
    aptr += 16; bptr += 16;
    __syncthreads();
    As[kq + 0][lr] = av0.x; As[kq + 1][lr] = av0.y;
    As[kq + 2][lr] = av0.z; As[kq + 3][lr] = av0.w;
    As[kq + 4][lr] = av1.x; As[kq + 5][lr] = av1.y;
    As[kq + 6][lr] = av1.z; As[kq + 7][lr] = av1.w;
    Bs[kq + 0][lr] = bv0.x; Bs[kq + 1][lr] = bv0.y;
    Bs[kq + 2][lr] = bv0.z; Bs[kq + 3][lr] = bv0.w;
    Bs[kq + 4][lr] = bv1.x; Bs[kq + 5][lr] = bv1.y;
    Bs[kq + 6][lr] = bv1.z; Bs[kq + 7][lr] = bv1.w;
    __syncthreads();
#pragma unroll
    for (int k = 0; k < 16; ++k) {
      float4 a0 = *(const float4*)&As[k][m0];
      float4 a1 = *(const float4*)&As[k][m0 + 4];
      float4 b0 = *(const float4*)&Bs[k][n0];
      float4 b1 = *(const float4*)&Bs[k][n0 + 4];
      float aa[8] = {a0.x, a0.y, a0.z, a0.w, a1.x, a1.y, a1.z, a1.w};
      float bb[8] = {b0.x, b0.y, b0.z, b0.w, b1.x, b1.y, b1.z, b1.w};
#pragma unroll
      for (int i = 0; i < 8; ++i)
#pragma unroll
        for (int j = 0; j < 8; ++j) acc[i][j] += aa[i] * bb[j];
    }
  }
  float bb[8];
#pragma unroll
  for (int j = 0; j < 8; ++j) bb[j] = bi[col0 + n0 + j];
#pragma unroll
  for (int i = 0; i < 8; ++i) {
    float* cp = cbase + (long)(m0 + i) * c_stride + col0 + n0;
    float4 c0 = {acc[i][0] + bb[0], acc[i][1] + bb[1], acc[i][2] + bb[2], acc[i][3] + bb[3]};
    float4 c1 = {acc[i][4] + bb[4], acc[i][5] + bb[5], acc[i][6] + bb[6], acc[i][7] + bb[7]};
    *(float4*)(cp) = c0;
    *(float4*)(cp + 4) = c1;
  }
}

__global__ __launch_bounds__(256, 2) void attn_f32_kernel(
    float* __restrict__ Q, const float* __restrict__ K, const float* __restrict__ V) {
  int n = blockIdx.x >> 4, h = blockIdx.x & 15;
  int t = threadIdx.x;
  __shared__ float Kc[64][68];
  __shared__ float Vc[64][68];
  float4 qv[16];
  const float* qrow = Q + ((long)(n * BS) + t) * D_ + h * HD;
#pragma unroll
  for (int e = 0; e < 16; ++e) qv[e] = *(const float4*)(qrow + e * 4);
  float m = -3e38f, l = 0.f;
  float4 o4[16];
#pragma unroll
  for (int e = 0; e < 16; ++e) o4[e] = {0.f, 0.f, 0.f, 0.f};
  int sj = t >> 2, se = (t & 3) * 16;
  for (int c = 0; c < 4; ++c) {
    __syncthreads();
    const float* kp = K + ((long)(n * BS + c * 64 + sj)) * D_ + h * HD + se;
    const float* vp = V + ((long)(n * BS + c * 64 + sj)) * D_ + h * HD + se;
#pragma unroll
    for (int i = 0; i < 4; ++i) {
      *(float4*)&Kc[sj][se + i * 4] = *(const float4*)(kp + i * 4);
      *(float4*)&Vc[sj][se + i * 4] = *(const float4*)(vp + i * 4);
    }
    __syncthreads();
    for (int j = 0; j < 64; ++j) {
      float s = 0.f;
#pragma unroll
      for (int e = 0; e < 16; ++e) {
        float4 kv = *(const float4*)&Kc[j][e * 4];
        s += qv[e].x * kv.x + qv[e].y * kv.y + qv[e].z * kv.z + qv[e].w * kv.w;
      }
      s *= 0.125f;
      if (s > m) {
        float sc = __expf(m - s);
        l *= sc;
#pragma unroll
        for (int e = 0; e < 16; ++e) {
          o4[e].x *= sc; o4[e].y *= sc; o4[e].z *= sc; o4[e].w *= sc;
        }
        m = s;
      }
      float p = __expf(s - m);
      l += p;
#pragma unroll
      for (int e = 0; e < 16; ++e) {
        float4 vv = *(const float4*)&Vc[j][e * 4];
        o4[e].x += p * vv.x; o4[e].y += p * vv.y;
        o4[e].z += p * vv.z; o4[e].w += p * vv.w;
      }
    }
  }
  float inv = 1.f / l;
  float* orow = Q + ((long)(n * BS) + t) * D_ + h * HD;
#pragma unroll
  for (int e = 0; e < 16; ++e) {
    float4 ov = {o4[e].x * inv, o4[e].y * inv, o4[e].z * inv, o4[e].w * inv};
    *(float4*)(orow + e * 4) = ov;
  }
}

// ---------------- launch ----------------
extern "C" void kernel_launch(void* const* d_in, const int* in_sizes, int n_in,
                              void* d_out, int out_size, void* d_ws, size_t ws_size,
                              hipStream_t stream) {
  (void)in_sizes; (void)n_in; (void)out_size;
  const float* x  = (const float*)d_in[0];
  const float* Wq = (const float*)d_in[1];
  const float* bq = (const float*)d_in[2];
  const float* Wk = (const float*)d_in[3];
  const float* bk = (const float*)d_in[4];
  const float* Wv = (const float*)d_in[5];
  const float* bv = (const float*)d_in[6];
  const float* Wo = (const float*)d_in[7];
  const float* bo = (const float*)d_in[8];
  float* out = (float*)d_out;
  char* ws = (char*)d_ws;

  // small scratch (1 MB region)
  float* xbf  = (float*)(ws);                   // 64x1024
  float* qbf  = (float*)(ws + 262144);
  float* kbf  = (float*)(ws + 524288);
  float* lgf  = (float*)(ws + 786432);
  int*   perm = (int*)(ws + 790528);

  const size_t NW  = (size_t)D_ * D_;           // 1,048,576
  const size_t NG  = (size_t)2 * S_ * D_;       // 8,388,608 elems per 2-batch group
  const size_t NX  = (size_t)S_ * B_ * D_;      // 16,777,216 elems of x
  const size_t SM  = 1 << 20;

  // fast-path layout: total = 152,043,520 B (same proven footprint as before)
  size_t off = SM;
  u16* whi  = (u16*)(ws + off); off += 3 * NW * 2;
  u16* wlo  = (u16*)(ws + off); off += 3 * NW * 2;
  u16* wohi = (u16*)(ws + off); off += NW * 2;
  u16* wolo = (u16*)(ws + off); off += NW * 2;
  u16* xhi  = (u16*)(ws + off); off += NX * 2;
  u16* xlo  = (u16*)(ws + off); off += NX * 2;
  u16* Qbf  = (u16*)(ws + off); off += NG * 2;
  u16* Khi  = (u16*)(ws + off); off += NG * 2;
  u16* Klo  = (u16*)(ws + off); off += NG * 2;
  u16* Vbf  = (u16*)(ws + off); off += NG * 2;
  const size_t need = off;

  // aliases: attn output reuses Q/V bf16 buffers (dead at that point per-group)
  u16* aohi = Vbf;
  u16* aolo = Qbf;

  // routing partials live in dead Qbf space on the fast path
  float* xbp = (float*)Qbf;   // 512 x 1024 f32 = 2 MB
  if (ws_size >= need) {
    mean1_kernel<<<512, 256, 0, stream>>>(x, xbp);
    mean2_kernel<<<64, 256, 0, stream>>>(xbp, xbf);
  } else {
    mean1_kernel<<<512, 256, 0, stream>>>(x, (float*)(ws + SM));
    mean2_kernel<<<64, 256, 0, stream>>>((float*)(ws + SM), xbf);
  }
  qkblk2_kernel<<<64, 256, 0, stream>>>(xbf, Wq, bq, Wk, bk, qbf, kbf);
  logits_kernel<<<256, 256, 0, stream>>>(qbf, kbf, lgf);
  sinkhorn_kernel<<<4, 256, 0, stream>>>(lgf, perm);

  if (ws_size >= need) {
    xsplit_kernel<<<16384, 256, 0, stream>>>(x, xhi, xlo);
    wsplit_kernel<<<dim3(1024, 4), 256, 0, stream>>>(Wq, Wk, Wv, Wo, whi, wlo, wohi, wolo);
    for (int grp = 0; grp < 2; ++grp) {
      gemm_qkv_kernel<<<dim3(8, 64, 3), 256, 0, stream>>>(
          xhi, xlo, whi, wlo, bq, bk, bv, Qbf, Khi, Klo, Vbf, perm, grp);
      attn_mfma_kernel<<<512, 256, 0, stream>>>(Qbf, Khi, Klo, Vbf, aohi, aolo);
      gemm_out_kernel<<<dim3(8, 64), 256, 0, stream>>>(
          aohi, aolo, wohi, wolo, bo, out, grp);
    }
  } else {
    // Tier C: proven fp32 path (49 MB)
    float* Qb = (float*)(ws + 4 * SM);
    float* Kb = Qb + (size_t)S_ * D_;
    float* Vb = Kb + (size_t)S_ * D_;
    for (int b = 0; b < B_; ++b) {
      gemm_f32_kernel<<<dim3(8, 32, 3), 256, 0, stream>>>(
          x, Wq, Wk, Wv, bq, bk, bv, Qb, Kb, Vb, perm, b, 0);
      attn_f32_kernel<<<256, 256, 0, stream>>>(Qb, Kb, Vb);
      gemm_f32_kernel<<<dim3(8, 32, 1), 256, 0, stream>>>(
          Qb, Wo, Wo, Wo, bo, bo, bo, out, out, out, perm, b, 1);
    }
  }
}

// Round 6
// 699.021 us; speedup vs baseline: 1.1956x; 1.1956x over previous
//
#include <hip/hip_runtime.h>
#include <math.h>

typedef unsigned short u16;
typedef __bf16 bf16t;
typedef bf16t bf16x8 __attribute__((ext_vector_type(8)));
typedef u16 u16x8 __attribute__((ext_vector_type(8)));
typedef float f32x4 __attribute__((ext_vector_type(4)));

#define D_ 1024
#define S_ 4096
#define B_ 4
#define NB 16
#define BS 256
#define NH 16
#define HD 64

__device__ __forceinline__ float bfu2f(u16 u) {
  unsigned int x = ((unsigned int)u) << 16;
  float f; __builtin_memcpy(&f, &x, 4); return f;
}
__device__ __forceinline__ u16 f2bfu(float f) {
  unsigned int x; __builtin_memcpy(&x, &f, 4);
  x += 0x7fffu + ((x >> 16) & 1u);   // RNE
  return (u16)(x >> 16);
}
__device__ __forceinline__ bf16x8 u2b16(u16x8 u) {
  bf16x8 r; __builtin_memcpy(&r, &u, 16); return r;
}
__device__ __forceinline__ void gld_lds16(const void* g, void* l) {
  __builtin_amdgcn_global_load_lds((__attribute__((address_space(1))) void*)g,
                                   (__attribute__((address_space(3))) void*)l, 16, 0, 0);
}

// ---------------- block means, two-stage ----------------
__global__ __launch_bounds__(256) void mean1_kernel(const float* __restrict__ x,
                                                    float* __restrict__ xbp) {
  int bx = blockIdx.x;
  int o = bx >> 3, p = bx & 7;
  int b = o >> 4, n = o & 15;
  int t = threadIdx.x;
  float4 acc = {0.f, 0.f, 0.f, 0.f};
  const float* xp = x + ((long)(n * BS + p * 32) * B_ + b) * D_ + t * 4;
  for (int s = 0; s < 32; ++s) {
    float4 u = *(const float4*)xp;
    acc.x += u.x; acc.y += u.y; acc.z += u.z; acc.w += u.w;
    xp += B_ * D_;
  }
  *(float4*)(xbp + (long)bx * D_ + t * 4) = acc;
}
__global__ __launch_bounds__(256) void mean2_kernel(const float* __restrict__ xbp,
                                                    float* __restrict__ xb) {
  int o = blockIdx.x, t = threadIdx.x;
  float4 acc = {0.f, 0.f, 0.f, 0.f};
#pragma unroll
  for (int p = 0; p < 8; ++p) {
    float4 u = *(const float4*)(xbp + (long)(o * 8 + p) * D_ + t * 4);
    acc.x += u.x; acc.y += u.y; acc.z += u.z; acc.w += u.w;
  }
  float4 r = {acc.x * (1.f / BS), acc.y * (1.f / BS), acc.z * (1.f / BS), acc.w * (1.f / BS)};
  *(float4*)(xb + (long)o * D_ + t * 4) = r;
}

// ---------------- q_blk / k_blk ----------------
__global__ __launch_bounds__(256) void qkblk2_kernel(const float* __restrict__ xb,
    const float* __restrict__ Wq, const float* __restrict__ bq,
    const float* __restrict__ Wk, const float* __restrict__ bk,
    float* __restrict__ qb, float* __restrict__ kb) {
  int m = blockIdx.x >> 5, ct = blockIdx.x & 31;
  const float* W  = m ? Wk : Wq;
  const float* bi = m ? bk : bq;
  float* out      = m ? kb : qb;
  __shared__ float As[64][132];
  __shared__ float Ws[32][132];
  int t = threadIdx.x;
  int col = t & 31, rg = t >> 5;
  float acc[8];
#pragma unroll
  for (int i = 0; i < 8; ++i) acc[i] = 0.f;
  int srow = t >> 2, sks = (t & 3) * 32;
  for (int kc = 0; kc < 8; ++kc) {
    int k0 = kc * 128;
    __syncthreads();
#pragma unroll
    for (int j = 0; j < 8; ++j)
      *(float4*)&As[srow][sks + j * 4] = *(const float4*)(xb + (long)srow * D_ + k0 + sks + j * 4);
    if (t < 128) {
      int c = t >> 2, ks = (t & 3) * 32;
#pragma unroll
      for (int j = 0; j < 8; ++j)
        *(float4*)&Ws[c][ks + j * 4] =
            *(const float4*)(W + (long)(ct * 32 + c) * D_ + k0 + ks + j * 4);
    }
    __syncthreads();
#pragma unroll
    for (int k4 = 0; k4 < 32; ++k4) {
      float4 wv = *(const float4*)&Ws[col][k4 * 4];
#pragma unroll
      for (int i = 0; i < 8; ++i) {
        float4 av = *(const float4*)&As[rg * 8 + i][k4 * 4];
        acc[i] += av.x * wv.x + av.y * wv.y + av.z * wv.z + av.w * wv.w;
      }
    }
  }
  float bv = bi[ct * 32 + col];
#pragma unroll
  for (int i = 0; i < 8; ++i)
    out[(long)(rg * 8 + i) * D_ + ct * 32 + col] = acc[i] + bv;
}

// ---------------- logits ----------------
__global__ __launch_bounds__(256) void logits_kernel(const float* __restrict__ qb,
                                                     const float* __restrict__ kb,
                                                     float* __restrict__ lg) {
  int idx = blockIdx.x * 4 + (threadIdx.x >> 6);
  int b = idx >> 8, n = (idx >> 4) & 15, m = idx & 15;
  int lane = threadIdx.x & 63;
  float acc = 0.f;
  const float* qp = qb + (b * 16 + n) * D_ + lane;
  const float* kp = kb + (b * 16 + m) * D_ + lane;
#pragma unroll
  for (int kk = 0; kk < 16; ++kk) acc += qp[kk * 64] * kp[kk * 64];
#pragma unroll
  for (int mm = 1; mm < 64; mm <<= 1) acc += __shfl_xor(acc, mm);
  if (lane == 0) lg[idx] = acc * (1.f / 32.f);
}

// ---------------- Sinkhorn + argmax ----------------
__global__ __launch_bounds__(256) void sinkhorn_kernel(const float* __restrict__ lg,
                                                       int* __restrict__ perm) {
  int b = blockIdx.x;
  __shared__ float L[16][17];
  int t = threadIdx.x;
  int n = t >> 4, m = t & 15;
  L[n][m] = lg[b * 256 + t];
  __syncthreads();
  for (int it = 0; it < 5; ++it) {
    float mx = -3e38f;
#pragma unroll
    for (int i = 0; i < 16; ++i) mx = fmaxf(mx, L[n][i]);
    float sm = 0.f;
#pragma unroll
    for (int i = 0; i < 16; ++i) sm += expf(L[n][i] - mx);
    float lse = mx + logf(sm);
    __syncthreads();
    L[n][m] -= lse;
    __syncthreads();
    mx = -3e38f;
#pragma unroll
    for (int i = 0; i < 16; ++i) mx = fmaxf(mx, L[i][m]);
    sm = 0.f;
#pragma unroll
    for (int i = 0; i < 16; ++i) sm += expf(L[i][m] - mx);
    lse = mx + logf(sm);
    __syncthreads();
    L[n][m] -= lse;
    __syncthreads();
  }
  if (t < 16) {
    float best = -3e38f; int bi = 0;
#pragma unroll
    for (int i = 0; i < 16; ++i) {
      float v = L[t][i];
      if (v > best) { best = v; bi = i; }
    }
    perm[b * 16 + t] = bi;
  }
}

// ---------------- merged weight split: 4 matrices -> hi/lo bf16 ----------------
__global__ __launch_bounds__(256) void wsplit_kernel(
    const float* __restrict__ Wq, const float* __restrict__ Wk,
    const float* __restrict__ Wv, const float* __restrict__ Wo,
    u16* __restrict__ whi, u16* __restrict__ wlo,
    u16* __restrict__ wohi, u16* __restrict__ wolo) {
  const size_t NW = (size_t)D_ * D_;
  int z = blockIdx.y;
  const float* src = (z == 0) ? Wq : (z == 1) ? Wk : (z == 2) ? Wv : Wo;
  u16* dh = (z < 3) ? (whi + (size_t)z * NW) : wohi;
  u16* dl = (z < 3) ? (wlo + (size_t)z * NW) : wolo;
  long i = (long)blockIdx.x * 256 + threadIdx.x;
  float4 v = ((const float4*)src)[i];
  ushort4 h, l;
  h.x = f2bfu(v.x); l.x = f2bfu(v.x - bfu2f(h.x));
  h.y = f2bfu(v.y); l.y = f2bfu(v.y - bfu2f(h.y));
  h.z = f2bfu(v.z); l.z = f2bfu(v.z - bfu2f(h.z));
  h.w = f2bfu(v.w); l.w = f2bfu(v.w - bfu2f(h.w));
  ((ushort4*)dh)[i] = h;
  ((ushort4*)dl)[i] = l;
}

// ---------------- x split: (S,B,D) fp32 -> hi/lo bf16, once ----------------
__global__ __launch_bounds__(256) void xsplit_kernel(const float* __restrict__ x,
    u16* __restrict__ xhi, u16* __restrict__ xlo) {
  long i = (long)blockIdx.x * 256 + threadIdx.x;
  float4 v = ((const float4*)x)[i];
  ushort4 h, l;
  h.x = f2bfu(v.x); l.x = f2bfu(v.x - bfu2f(h.x));
  h.y = f2bfu(v.y); l.y = f2bfu(v.y - bfu2f(h.y));
  h.z = f2bfu(v.z); l.z = f2bfu(v.z - bfu2f(h.z));
  h.w = f2bfu(v.w); l.w = f2bfu(v.w - bfu2f(h.w));
  ((ushort4*)xhi)[i] = h;
  ((ushort4*)xlo)[i] = l;
}

// ---------------- QKV GEMM v5: round-3 single-buffer structure + XCD-aware (T1) ---
// 1D grid 1536. XCD (hw&7) owns y-panels [xcd*8, xcd*8+8); within an XCD the 24
// (x,z) tiles of one A panel run consecutively -> A panel fetched from HBM once,
// L2-hot for its consumers. Bijective: 8 xcd x 8 yl x 24 rem.
// Kernel body identical to the round-3-proven version (0 bank conflicts, 170 us).
__global__ __launch_bounds__(256, 3) void gemm_qkv_kernel(
    const u16* __restrict__ xhi, const u16* __restrict__ xlo,
    const u16* __restrict__ whi, const u16* __restrict__ wlo,
    const float* __restrict__ bq, const float* __restrict__ bk, const float* __restrict__ bv,
    u16* __restrict__ Qbf, u16* __restrict__ Khi, u16* __restrict__ Klo,
    u16* __restrict__ Vbf, const int* __restrict__ perm, int grp) {
  int hw = blockIdx.x;
  int xcd = hw & 7, idx = hw >> 3;       // idx 0..191
  int yl = idx / 24, rem = idx - yl * 24;
  int z = rem >> 3, xt = rem & 7;
  int y = xcd * 8 + yl;                  // 0..63
  const u16* Wh = whi + (size_t)z * (D_ * D_);
  const u16* Wl = wlo + (size_t)z * (D_ * D_);
  const float* bi = (z == 0) ? bq : (z == 1) ? bk : bv;
  int g = y >> 5, st = y & 31;
  int b = grp * 2 + g;
  int col0 = xt * 128;
  int n = st >> 1;
  int sb = perm[b * NB + n];
  const long a_stride = (long)B_ * D_;
  long a_off = ((long)(sb * BS + (st & 1) * 128) * B_ + b) * D_;
  const u16* Ahg = xhi + a_off;
  const u16* Alg = xlo + a_off;

  __shared__ u16 Ash[4096], Asl[4096], Bsh[4096], Bsl[4096];
  int t = threadIdx.x;
  int w = t >> 6, lane = t & 63, quad = lane >> 4, l15 = lane & 15;
  int wm = w >> 1, wn = w & 1;
  f32x4 acc[4][4];
#pragma unroll
  for (int i = 0; i < 4; ++i)
#pragma unroll
    for (int j = 0; j < 4; ++j) acc[i][j] = {0.f, 0.f, 0.f, 0.f};

  // staging: 512 chunks of 16B per buffer; chunk ch -> row ch>>2, phys kchunk ch&3,
  // global kchunk = (ch&3) ^ ((ch>>3)&3)
  int ch0 = t, ch1 = t + 256;
  int r0 = ch0 >> 2, kc0 = ((ch0 & 3) ^ ((ch0 >> 3) & 3)) * 8;
  int r1 = ch1 >> 2, kc1 = ((ch1 & 3) ^ ((ch1 >> 3) & 3)) * 8;
  int cswz = (quad ^ ((l15 >> 1) & 3)) * 8;

  for (int k0 = 0; k0 < D_; k0 += 32) {
    gld_lds16(Ahg + (long)r0 * a_stride + k0 + kc0, Ash + ch0 * 8);
    gld_lds16(Ahg + (long)r1 * a_stride + k0 + kc1, Ash + ch1 * 8);
    gld_lds16(Alg + (long)r0 * a_stride + k0 + kc0, Asl + ch0 * 8);
    gld_lds16(Alg + (long)r1 * a_stride + k0 + kc1, Asl + ch1 * 8);
    gld_lds16(Wh + (long)(col0 + r0) * D_ + k0 + kc0, Bsh + ch0 * 8);
    gld_lds16(Wh + (long)(col0 + r1) * D_ + k0 + kc1, Bsh + ch1 * 8);
    gld_lds16(Wl + (long)(col0 + r0) * D_ + k0 + kc0, Bsl + ch0 * 8);
    gld_lds16(Wl + (long)(col0 + r1) * D_ + k0 + kc1, Bsl + ch1 * 8);
    __syncthreads();
    bf16x8 ah[4], al[4], bh[4], bl[4];
#pragma unroll
    for (int i = 0; i < 4; ++i) {
      ah[i] = *(const bf16x8*)(Ash + (wm * 64 + i * 16 + l15) * 32 + cswz);
      al[i] = *(const bf16x8*)(Asl + (wm * 64 + i * 16 + l15) * 32 + cswz);
    }
#pragma unroll
    for (int j = 0; j < 4; ++j) {
      bh[j] = *(const bf16x8*)(Bsh + (wn * 64 + j * 16 + l15) * 32 + cswz);
      bl[j] = *(const bf16x8*)(Bsl + (wn * 64 + j * 16 + l15) * 32 + cswz);
    }
#pragma unroll
    for (int i = 0; i < 4; ++i)
#pragma unroll
      for (int j = 0; j < 4; ++j) {
        acc[i][j] = __builtin_amdgcn_mfma_f32_16x16x32_bf16(al[i], bh[j], acc[i][j], 0, 0, 0);
        acc[i][j] = __builtin_amdgcn_mfma_f32_16x16x32_bf16(ah[i], bl[j], acc[i][j], 0, 0, 0);
        acc[i][j] = __builtin_amdgcn_mfma_f32_16x16x32_bf16(ah[i], bh[j], acc[i][j], 0, 0, 0);
      }
    __syncthreads();
  }
#pragma unroll
  for (int j = 0; j < 4; ++j) {
    float bvv = bi[col0 + wn * 64 + j * 16 + l15];
#pragma unroll
    for (int i = 0; i < 4; ++i) {
      int row = wm * 64 + i * 16 + quad * 4;
      long base = ((long)g * S_ + st * 128 + row) * D_ + col0 + wn * 64 + j * 16 + l15;
#pragma unroll
      for (int r = 0; r < 4; ++r) {
        float val = acc[i][j][r] + bvv;
        long a = base + (long)r * D_;
        if (z == 0) {
          Qbf[a] = f2bfu(val * 0.125f);
        } else if (z == 1) {
          u16 hh = f2bfu(val);
          Khi[a] = hh;
          Klo[a] = f2bfu(val - bfu2f(hh));
        } else {
          Vbf[a] = f2bfu(val);
        }
      }
    }
  }
}

// ---------------- out GEMM: round-3 structure + XCD-aware (T1), 1D grid 512 -------
__global__ __launch_bounds__(256, 3) void gemm_out_kernel(
    const u16* __restrict__ Ahi, const u16* __restrict__ Alo,
    const u16* __restrict__ wohi, const u16* __restrict__ wolo,
    const float* __restrict__ bo, float* __restrict__ out, int grp) {
  int hw = blockIdx.x;
  int xcd = hw & 7, idx = hw >> 3;       // idx 0..63
  int yl = idx >> 3, xt = idx & 7;
  int y = xcd * 8 + yl;                  // 0..63
  int g = y >> 5, st = y & 31;
  int b = grp * 2 + g;
  int col0 = xt * 128;
  long a_off = ((long)g * S_ + st * 128) * D_;
  const u16* Ah = Ahi + a_off;
  const u16* Al = Alo + a_off;
  float* cbase = out + ((long)(st * 128) * B_ + b) * D_;
  const long c_stride = (long)B_ * D_;

  __shared__ u16 Ash[4096], Asl[4096], Bsh[4096], Bsl[4096];
  int t = threadIdx.x;
  int w = t >> 6, lane = t & 63, quad = lane >> 4, l15 = lane & 15;
  int wm = w >> 1, wn = w & 1;
  f32x4 acc[4][4];
#pragma unroll
  for (int i = 0; i < 4; ++i)
#pragma unroll
    for (int j = 0; j < 4; ++j) acc[i][j] = {0.f, 0.f, 0.f, 0.f};

  int ch0 = t, ch1 = t + 256;
  int r0 = ch0 >> 2, kc0 = ((ch0 & 3) ^ ((ch0 >> 3) & 3)) * 8;
  int r1 = ch1 >> 2, kc1 = ((ch1 & 3) ^ ((ch1 >> 3) & 3)) * 8;
  int cswz = (quad ^ ((l15 >> 1) & 3)) * 8;

  for (int k0 = 0; k0 < D_; k0 += 32) {
    gld_lds16(Ah + (long)r0 * D_ + k0 + kc0, Ash + ch0 * 8);
    gld_lds16(Ah + (long)r1 * D_ + k0 + kc1, Ash + ch1 * 8);
    gld_lds16(Al + (long)r0 * D_ + k0 + kc0, Asl + ch0 * 8);
    gld_lds16(Al + (long)r1 * D_ + k0 + kc1, Asl + ch1 * 8);
    gld_lds16(wohi + (long)(col0 + r0) * D_ + k0 + kc0, Bsh + ch0 * 8);
    gld_lds16(wohi + (long)(col0 + r1) * D_ + k0 + kc1, Bsh + ch1 * 8);
    gld_lds16(wolo + (long)(col0 + r0) * D_ + k0 + kc0, Bsl + ch0 * 8);
    gld_lds16(wolo + (long)(col0 + r1) * D_ + k0 + kc1, Bsl + ch1 * 8);
    __syncthreads();
    bf16x8 ah[4], al[4], bh[4], bl[4];
#pragma unroll
    for (int i = 0; i < 4; ++i) {
      ah[i] = *(const bf16x8*)(Ash + (wm * 64 + i * 16 + l15) * 32 + cswz);
      al[i] = *(const bf16x8*)(Asl + (wm * 64 + i * 16 + l15) * 32 + cswz);
    }
#pragma unroll
    for (int j = 0; j < 4; ++j) {
      bh[j] = *(const bf16x8*)(Bsh + (wn * 64 + j * 16 + l15) * 32 + cswz);
      bl[j] = *(const bf16x8*)(Bsl + (wn * 64 + j * 16 + l15) * 32 + cswz);
    }
#pragma unroll
    for (int i = 0; i < 4; ++i)
#pragma unroll
      for (int j = 0; j < 4; ++j) {
        acc[i][j] = __builtin_amdgcn_mfma_f32_16x16x32_bf16(al[i], bh[j], acc[i][j], 0, 0, 0);
        acc[i][j] = __builtin_amdgcn_mfma_f32_16x16x32_bf16(ah[i], bl[j], acc[i][j], 0, 0, 0);
        acc[i][j] = __builtin_amdgcn_mfma_f32_16x16x32_bf16(ah[i], bh[j], acc[i][j], 0, 0, 0);
      }
    __syncthreads();
  }
#pragma unroll
  for (int j = 0; j < 4; ++j) {
    float bvv = bo[col0 + wn * 64 + j * 16 + l15];
#pragma unroll
    for (int i = 0; i < 4; ++i) {
      int row = wm * 64 + i * 16 + quad * 4;
      long base = (long)row * c_stride + col0 + wn * 64 + j * 16 + l15;
#pragma unroll
      for (int r = 0; r < 4; ++r)
        cbase[base + (long)r * c_stride] = acc[i][j][r] + bvv;
    }
  }
}

// ---------------- block-local attention, MFMA flash, bf16 inputs ----------------
// Inputs already bf16: Qbf pre-scaled, Khi/Klo split, Vbf. No conversion VALU.
// aohi aliases Vbf, aolo aliases Qbf (per-workgroup regions disjoint; all reads of a
// region complete before its epilogue write).
__global__ __launch_bounds__(256, 2) void attn_mfma_kernel(
    const u16* __restrict__ Qbf, const u16* __restrict__ KhiG, const u16* __restrict__ KloG,
    const u16* __restrict__ Vbf, u16* __restrict__ aohi, u16* __restrict__ aolo) {
  int g = blockIdx.x >> 8;
  int n = (blockIdx.x >> 4) & 15, h = blockIdx.x & 15;
  long rbase = (long)g * S_ + n * BS;
  int t = threadIdx.x;
  int w = t >> 6, lane = t & 63, quad = lane >> 4, l15 = lane & 15;

  __shared__ __attribute__((aligned(16))) u16 Khi[64][72];
  __shared__ __attribute__((aligned(16))) u16 Klo[64][72];
  __shared__ __attribute__((aligned(16))) u16 Vt[64][72];   // transposed: [d][key]
  __shared__ __attribute__((aligned(16))) u16 Pw[4][64][72];

  bf16x8 vones;
  {
    u16x8 uo;
#pragma unroll
    for (int e = 0; e < 8; ++e) uo[e] = 0x3F80u;  // bf16 1.0
    vones = u2b16(uo);
  }

  // Q fragments: direct bf16 load (pre-scaled by 0.125 in gemm_qkv)
  bf16x8 qf[4][2];
#pragma unroll
  for (int i = 0; i < 4; ++i)
#pragma unroll
    for (int ks = 0; ks < 2; ++ks)
      qf[i][ks] = u2b16(*(const u16x8*)(Qbf +
          (rbase + w * 64 + i * 16 + l15) * (long)D_ + h * HD + ks * 32 + quad * 8));

  f32x4 acc[4][4];
  f32x4 accl[4];
  float m[4][4];
#pragma unroll
  for (int i = 0; i < 4; ++i) {
    accl[i] = {0.f, 0.f, 0.f, 0.f};
#pragma unroll
    for (int j = 0; j < 4; ++j) {
      acc[i][j] = {0.f, 0.f, 0.f, 0.f};
      m[i][j] = -3e38f;
    }
  }

  int skey = t >> 2, sd0 = (t & 3) * 16;

#pragma unroll 1
  for (int c = 0; c < 4; ++c) {
    __syncthreads();
    // ---- stage K hi/lo (copy) and V^T (scatter) ----
    {
      long roff = (rbase + c * 64 + skey) * (long)D_ + h * HD + sd0;
      u16x8 h0 = *(const u16x8*)(KhiG + roff);
      u16x8 h1 = *(const u16x8*)(KhiG + roff + 8);
      u16x8 l0 = *(const u16x8*)(KloG + roff);
      u16x8 l1 = *(const u16x8*)(KloG + roff + 8);
      *(u16x8*)&Khi[skey][sd0] = h0;
      *(u16x8*)&Khi[skey][sd0 + 8] = h1;
      *(u16x8*)&Klo[skey][sd0] = l0;
      *(u16x8*)&Klo[skey][sd0 + 8] = l1;
      u16x8 v0 = *(const u16x8*)(Vbf + roff);
      u16x8 v1 = *(const u16x8*)(Vbf + roff + 8);
#pragma unroll
      for (int e = 0; e < 8; ++e) {
        Vt[sd0 + e][skey] = v0[e];
        Vt[sd0 + 8 + e][skey] = v1[e];
      }
    }
    __syncthreads();

    // ---- S = Q K^T (2-term) ----
    f32x4 s[4][4];
#pragma unroll
    for (int i = 0; i < 4; ++i)
#pragma unroll
      for (int j = 0; j < 4; ++j) s[i][j] = {0.f, 0.f, 0.f, 0.f};
#pragma unroll
    for (int ks = 0; ks < 2; ++ks)
#pragma unroll
      for (int j = 0; j < 4; ++j) {
        bf16x8 kh = *(const bf16x8*)&Khi[j * 16 + l15][ks * 32 + quad * 8];
        bf16x8 kl = *(const bf16x8*)&Klo[j * 16 + l15][ks * 32 + quad * 8];
#pragma unroll
        for (int i = 0; i < 4; ++i) {
          s[i][j] = __builtin_amdgcn_mfma_f32_16x16x32_bf16(qf[i][ks], kl, s[i][j], 0, 0, 0);
          s[i][j] = __builtin_amdgcn_mfma_f32_16x16x32_bf16(qf[i][ks], kh, s[i][j], 0, 0, 0);
        }
      }

    // ---- online softmax; P -> LDS (bf16) ----
#pragma unroll
    for (int i = 0; i < 4; ++i)
#pragma unroll
      for (int r = 0; r < 4; ++r) {
        float mc = fmaxf(fmaxf(s[i][0][r], s[i][1][r]), fmaxf(s[i][2][r], s[i][3][r]));
#pragma unroll
        for (int mk = 1; mk < 16; mk <<= 1) mc = fmaxf(mc, __shfl_xor(mc, mk));
        float mn = fmaxf(m[i][r], mc);
        float sc = __expf(m[i][r] - mn);
        m[i][r] = mn;
#pragma unroll
        for (int j = 0; j < 4; ++j) {
          float p = __expf(s[i][j][r] - mn);
          Pw[w][i * 16 + quad * 4 + r][j * 16 + l15] = f2bfu(p);
        }
        accl[i][r] *= sc;
#pragma unroll
        for (int jd = 0; jd < 4; ++jd) acc[i][jd][r] *= sc;
      }
    __syncthreads();

    // ---- O += P V ; denom += P * ones ----
#pragma unroll
    for (int ks = 0; ks < 2; ++ks) {
      bf16x8 pa[4], vb[4];
#pragma unroll
      for (int i = 0; i < 4; ++i)
        pa[i] = *(const bf16x8*)&Pw[w][i * 16 + l15][ks * 32 + quad * 8];
#pragma unroll
      for (int jd = 0; jd < 4; ++jd)
        vb[jd] = *(const bf16x8*)&Vt[jd * 16 + l15][ks * 32 + quad * 8];
#pragma unroll
      for (int i = 0; i < 4; ++i) {
#pragma unroll
        for (int jd = 0; jd < 4; ++jd)
          acc[i][jd] = __builtin_amdgcn_mfma_f32_16x16x32_bf16(pa[i], vb[jd], acc[i][jd], 0, 0, 0);
        accl[i] = __builtin_amdgcn_mfma_f32_16x16x32_bf16(pa[i], vones, accl[i], 0, 0, 0);
      }
    }
  }

  // ---- epilogue: normalize, split hi/lo, store ----
#pragma unroll
  for (int i = 0; i < 4; ++i) {
    float il[4];
#pragma unroll
    for (int r = 0; r < 4; ++r) il[r] = 1.f / accl[i][r];
#pragma unroll
    for (int jd = 0; jd < 4; ++jd)
#pragma unroll
      for (int r = 0; r < 4; ++r) {
        float f = acc[i][jd][r] * il[r];
        u16 hh = f2bfu(f);
        u16 ll = f2bfu(f - bfu2f(hh));
        long addr = (rbase + w * 64 + i * 16 + quad * 4 + r) * (long)D_ + h * HD + jd * 16 + l15;
        aohi[addr] = hh;
        aolo[addr] = ll;
      }
  }
}

// ================= Tier C fallback (proven fp32 path) =================
__global__ __launch_bounds__(256, 2) void gemm_f32_kernel(
    const float* __restrict__ A0,
    const float* __restrict__ W0, const float* __restrict__ W1, const float* __restrict__ W2,
    const float* __restrict__ bi0, const float* __restrict__ bi1, const float* __restrict__ bi2,
    float* __restrict__ O0, float* __restrict__ O1, float* __restrict__ O2,
    const int* __restrict__ perm, int b, int mode) {
  int z = blockIdx.z;
  const float* W  = (z == 0) ? W0 : (z == 1 ? W1 : W2);
  const float* bi = (z == 0) ? bi0 : (z == 1 ? bi1 : bi2);
  float* C        = (z == 0) ? O0 : (z == 1 ? O1 : O2);
  int st = blockIdx.y;
  int col0 = blockIdx.x * 128;
  const float* abase; float* cbase; long a_stride, c_stride;
  if (mode == 0) {
    int n = st >> 1;
    int sb = perm[b * NB + n];
    long a_row0 = (long)sb * BS + (st & 1) * 128;
    abase = A0 + (a_row0 * B_ + b) * D_;
    a_stride = (long)B_ * D_;
    cbase = C + (long)(st * 128) * D_;
    c_stride = D_;
  } else {
    abase = A0 + (long)(st * 128) * D_;
    a_stride = D_;
    cbase = C + ((long)(st * 128) * B_ + b) * D_;
    c_stride = (long)B_ * D_;
  }
  __shared__ float As[16][132];
  __shared__ float Bs[16][132];
  int t = threadIdx.x;
  int lr = t >> 1, kq = (t & 1) * 8;
  int m0 = (t >> 4) * 8, n0 = (t & 15) * 8;
  const float* aptr = abase + (long)lr * a_stride + kq;
  const float* bptr = W + (long)(col0 + lr) * D_ + kq;
  float acc[8][8];
#pragma unroll
  for (int i = 0; i < 8; ++i)
#pragma unroll
    for (int j = 0; j < 8; ++j) acc[i][j] = 0.f;
  for (int kt = 0; kt < D_ / 16; ++kt) {
    float4 av0 = *(const float4*)(aptr);
    float4 av1 = *(const float4*)(aptr + 4);
    float4 bv0 = *(const float4*)(bptr);
    float4 bv1 = *(const float4*)(bptr + 4);
    aptr += 16; bptr += 16;
    __syncthreads();
    As[kq + 0][lr] = av0.x; As[kq + 1][lr] = av0.y;
    As[kq + 2][lr] = av0.z; As[kq + 3][lr] = av0.w;
    As[kq + 4][lr] = av1.x; As[kq + 5][lr] = av1.y;
    As[kq + 6][lr] = av1.z; As[kq + 7][lr] = av1.w;
    Bs[kq + 0][lr] = bv0.x; Bs[kq + 1][lr] = bv0.y;
    Bs[kq + 2][lr] = bv0.z; Bs[kq + 3][lr] = bv0.w;
    Bs[kq + 4][lr] = bv1.x; Bs[kq + 5][lr] = bv1.y;
    Bs[kq + 6][lr] = bv1.z; Bs[kq + 7][lr] = bv1.w;
    __syncthreads();
#pragma unroll
    for (int k = 0; k < 16; ++k) {
      float4 a0 = *(const float4*)&As[k][m0];
      float4 a1 = *(const float4*)&As[k][m0 + 4];
      float4 b0 = *(const float4*)&Bs[k][n0];
      float4 b1 = *(const float4*)&Bs[k][n0 + 4];
      float aa[8] = {a0.x, a0.y, a0.z, a0.w, a1.x, a1.y, a1.z, a1.w};
      float bb[8] = {b0.x, b0.y, b0.z, b0.w, b1.x, b1.y, b1.z, b1.w};
#pragma unroll
      for (int i = 0; i < 8; ++i)
#pragma unroll
        for (int j = 0; j < 8; ++j) acc[i][j] += aa[i] * bb[j];
    }
  }
  float bb[8];
#pragma unroll
  for (int j = 0; j < 8; ++j) bb[j] = bi[col0 + n0 + j];
#pragma unroll
  for (int i = 0; i < 8; ++i) {
    float* cp = cbase + (long)(m0 + i) * c_stride + col0 + n0;
    float4 c0 = {acc[i][0] + bb[0], acc[i][1] + bb[1], acc[i][2] + bb[2], acc[i][3] + bb[3]};
    float4 c1 = {acc[i][4] + bb[4], acc[i][5] + bb[5], acc[i][6] + bb[6], acc[i][7] + bb[7]};
    *(float4*)(cp) = c0;
    *(float4*)(cp + 4) = c1;
  }
}

__global__ __launch_bounds__(256, 2) void attn_f32_kernel(
    float* __restrict__ Q, const float* __restrict__ K, const float* __restrict__ V) {
  int n = blockIdx.x >> 4, h = blockIdx.x & 15;
  int t = threadIdx.x;
  __shared__ float Kc[64][68];
  __shared__ float Vc[64][68];
  float4 qv[16];
  const float* qrow = Q + ((long)(n * BS) + t) * D_ + h * HD;
#pragma unroll
  for (int e = 0; e < 16; ++e) qv[e] = *(const float4*)(qrow + e * 4);
  float m = -3e38f, l = 0.f;
  float4 o4[16];
#pragma unroll
  for (int e = 0; e < 16; ++e) o4[e] = {0.f, 0.f, 0.f, 0.f};
  int sj = t >> 2, se = (t & 3) * 16;
  for (int c = 0; c < 4; ++c) {
    __syncthreads();
    const float* kp = K + ((long)(n * BS + c * 64 + sj)) * D_ + h * HD + se;
    const float* vp = V + ((long)(n * BS + c * 64 + sj)) * D_ + h * HD + se;
#pragma unroll
    for (int i = 0; i < 4; ++i) {
      *(float4*)&Kc[sj][se + i * 4] = *(const float4*)(kp + i * 4);
      *(float4*)&Vc[sj][se + i * 4] = *(const float4*)(vp + i * 4);
    }
    __syncthreads();
    for (int j = 0; j < 64; ++j) {
      float s = 0.f;
#pragma unroll
      for (int e = 0; e < 16; ++e) {
        float4 kv = *(const float4*)&Kc[j][e * 4];
        s += qv[e].x * kv.x + qv[e].y * kv.y + qv[e].z * kv.z + qv[e].w * kv.w;
      }
      s *= 0.125f;
      if (s > m) {
        float sc = __expf(m - s);
        l *= sc;
#pragma unroll
        for (int e = 0; e < 16; ++e) {
          o4[e].x *= sc; o4[e].y *= sc; o4[e].z *= sc; o4[e].w *= sc;
        }
        m = s;
      }
      float p = __expf(s - m);
      l += p;
#pragma unroll
      for (int e = 0; e < 16; ++e) {
        float4 vv = *(const float4*)&Vc[j][e * 4];
        o4[e].x += p * vv.x; o4[e].y += p * vv.y;
        o4[e].z += p * vv.z; o4[e].w += p * vv.w;
      }
    }
  }
  float inv = 1.f / l;
  float* orow = Q + ((long)(n * BS) + t) * D_ + h * HD;
#pragma unroll
  for (int e = 0; e < 16; ++e) {
    float4 ov = {o4[e].x * inv, o4[e].y * inv, o4[e].z * inv, o4[e].w * inv};
    *(float4*)(orow + e * 4) = ov;
  }
}

// ---------------- launch ----------------
extern "C" void kernel_launch(void* const* d_in, const int* in_sizes, int n_in,
                              void* d_out, int out_size, void* d_ws, size_t ws_size,
                              hipStream_t stream) {
  (void)in_sizes; (void)n_in; (void)out_size;
  const float* x  = (const float*)d_in[0];
  const float* Wq = (const float*)d_in[1];
  const float* bq = (const float*)d_in[2];
  const float* Wk = (const float*)d_in[3];
  const float* bk = (const float*)d_in[4];
  const float* Wv = (const float*)d_in[5];
  const float* bv = (const float*)d_in[6];
  const float* Wo = (const float*)d_in[7];
  const float* bo = (const float*)d_in[8];
  float* out = (float*)d_out;
  char* ws = (char*)d_ws;

  // small scratch (1 MB region)
  float* xbf  = (float*)(ws);                   // 64x1024
  float* qbf  = (float*)(ws + 262144);
  float* kbf  = (float*)(ws + 524288);
  float* lgf  = (float*)(ws + 786432);
  int*   perm = (int*)(ws + 790528);

  const size_t NW  = (size_t)D_ * D_;           // 1,048,576
  const size_t NG  = (size_t)2 * S_ * D_;       // 8,388,608 elems per 2-batch group
  const size_t NX  = (size_t)S_ * B_ * D_;      // 16,777,216 elems of x
  const size_t SM  = 1 << 20;

  // fast-path layout: total = 152,043,520 B (same proven footprint as before)
  size_t off = SM;
  u16* whi  = (u16*)(ws + off); off += 3 * NW * 2;
  u16* wlo  = (u16*)(ws + off); off += 3 * NW * 2;
  u16* wohi = (u16*)(ws + off); off += NW * 2;
  u16* wolo = (u16*)(ws + off); off += NW * 2;
  u16* xhi  = (u16*)(ws + off); off += NX * 2;
  u16* xlo  = (u16*)(ws + off); off += NX * 2;
  u16* Qbf  = (u16*)(ws + off); off += NG * 2;
  u16* Khi  = (u16*)(ws + off); off += NG * 2;
  u16* Klo  = (u16*)(ws + off); off += NG * 2;
  u16* Vbf  = (u16*)(ws + off); off += NG * 2;
  const size_t need = off;

  // aliases: attn output reuses Q/V bf16 buffers (dead at that point per-group)
  u16* aohi = Vbf;
  u16* aolo = Qbf;

  // routing partials live in dead Qbf space on the fast path
  float* xbp = (float*)Qbf;   // 512 x 1024 f32 = 2 MB
  if (ws_size >= need) {
    mean1_kernel<<<512, 256, 0, stream>>>(x, xbp);
    mean2_kernel<<<64, 256, 0, stream>>>(xbp, xbf);
  } else {
    mean1_kernel<<<512, 256, 0, stream>>>(x, (float*)(ws + SM));
    mean2_kernel<<<64, 256, 0, stream>>>((float*)(ws + SM), xbf);
  }
  qkblk2_kernel<<<64, 256, 0, stream>>>(xbf, Wq, bq, Wk, bk, qbf, kbf);
  logits_kernel<<<256, 256, 0, stream>>>(qbf, kbf, lgf);
  sinkhorn_kernel<<<4, 256, 0, stream>>>(lgf, perm);

  if (ws_size >= need) {
    xsplit_kernel<<<16384, 256, 0, stream>>>(x, xhi, xlo);
    wsplit_kernel<<<dim3(1024, 4), 256, 0, stream>>>(Wq, Wk, Wv, Wo, whi, wlo, wohi, wolo);
    for (int grp = 0; grp < 2; ++grp) {
      gemm_qkv_kernel<<<1536, 256, 0, stream>>>(
          xhi, xlo, whi, wlo, bq, bk, bv, Qbf, Khi, Klo, Vbf, perm, grp);
      attn_mfma_kernel<<<512, 256, 0, stream>>>(Qbf, Khi, Klo, Vbf, aohi, aolo);
      gemm_out_kernel<<<512, 256, 0, stream>>>(
          aohi, aolo, wohi, wolo, bo, out, grp);
    }
  } else {
    // Tier C: proven fp32 path (49 MB)
    float* Qb = (float*)(ws + 4 * SM);
    float* Kb = Qb + (size_t)S_ * D_;
    float* Vb = Kb + (size_t)S_ * D_;
    for (int b = 0; b < B_; ++b) {
      gemm_f32_kernel<<<dim3(8, 32, 3), 256, 0, stream>>>(
          x, Wq, Wk, Wv, bq, bk, bv, Qb, Kb, Vb, perm, b, 0);
      attn_f32_kernel<<<256, 256, 0, stream>>>(Qb, Kb, Vb);
      gemm_f32_kernel<<<dim3(8, 32, 1), 256, 0, stream>>>(
          Qb, Wo, Wo, Wo, bo, bo, bo, out, out, out, perm, b, 1);
    }
  }
}

// Round 7
// 686.830 us; speedup vs baseline: 1.2169x; 1.0178x over previous
//
#include <hip/hip_runtime.h>
#include <math.h>

typedef unsigned short u16;
typedef __bf16 bf16t;
typedef bf16t bf16x8 __attribute__((ext_vector_type(8)));
typedef u16 u16x8 __attribute__((ext_vector_type(8)));
typedef float f32x4 __attribute__((ext_vector_type(4)));

#define D_ 1024
#define S_ 4096
#define B_ 4
#define NB 16
#define BS 256
#define NH 16
#define HD 64

__device__ __forceinline__ float bfu2f(u16 u) {
  unsigned int x = ((unsigned int)u) << 16;
  float f; __builtin_memcpy(&f, &x, 4); return f;
}
__device__ __forceinline__ u16 f2bfu(float f) {
  unsigned int x; __builtin_memcpy(&x, &f, 4);
  x += 0x7fffu + ((x >> 16) & 1u);   // RNE
  return (u16)(x >> 16);
}
__device__ __forceinline__ bf16x8 u2b16(u16x8 u) {
  bf16x8 r; __builtin_memcpy(&r, &u, 16); return r;
}
__device__ __forceinline__ void gld_lds16(const void* g, void* l) {
  __builtin_amdgcn_global_load_lds((__attribute__((address_space(1))) void*)g,
                                   (__attribute__((address_space(3))) void*)l, 16, 0, 0);
}

// ---------------- block means, two-stage ----------------
// Tier C variant (no split buffers available)
__global__ __launch_bounds__(256) void mean1_kernel(const float* __restrict__ x,
                                                    float* __restrict__ xbp) {
  int bx = blockIdx.x;
  int o = bx >> 3, p = bx & 7;
  int b = o >> 4, n = o & 15;
  int t = threadIdx.x;
  float4 acc = {0.f, 0.f, 0.f, 0.f};
  const float* xp = x + ((long)(n * BS + p * 32) * B_ + b) * D_ + t * 4;
  for (int s = 0; s < 32; ++s) {
    float4 u = *(const float4*)xp;
    acc.x += u.x; acc.y += u.y; acc.z += u.z; acc.w += u.w;
    xp += B_ * D_;
  }
  *(float4*)(xbp + (long)bx * D_ + t * 4) = acc;
}
// fast-path variant: same reads & bit-identical sum order + hi/lo split store
// (replaces the separate xsplit pass -> one fewer full read of x)
__global__ __launch_bounds__(256) void mean1split_kernel(const float* __restrict__ x,
    float* __restrict__ xbp, u16* __restrict__ xhi, u16* __restrict__ xlo) {
  int bx = blockIdx.x;
  int o = bx >> 3, p = bx & 7;
  int b = o >> 4, n = o & 15;
  int t = threadIdx.x;
  float4 acc = {0.f, 0.f, 0.f, 0.f};
  long base = ((long)(n * BS + p * 32) * B_ + b) * D_ + t * 4;
  const float* xp = x + base;
  long idx = base;
  for (int s = 0; s < 32; ++s) {
    float4 u = *(const float4*)xp;
    acc.x += u.x; acc.y += u.y; acc.z += u.z; acc.w += u.w;
    ushort4 h, l;
    h.x = f2bfu(u.x); l.x = f2bfu(u.x - bfu2f(h.x));
    h.y = f2bfu(u.y); l.y = f2bfu(u.y - bfu2f(h.y));
    h.z = f2bfu(u.z); l.z = f2bfu(u.z - bfu2f(h.z));
    h.w = f2bfu(u.w); l.w = f2bfu(u.w - bfu2f(h.w));
    *(ushort4*)(xhi + idx) = h;
    *(ushort4*)(xlo + idx) = l;
    xp += B_ * D_;
    idx += B_ * D_;
  }
  *(float4*)(xbp + (long)bx * D_ + t * 4) = acc;
}
__global__ __launch_bounds__(256) void mean2_kernel(const float* __restrict__ xbp,
                                                    float* __restrict__ xb) {
  int o = blockIdx.x, t = threadIdx.x;
  float4 acc = {0.f, 0.f, 0.f, 0.f};
#pragma unroll
  for (int p = 0; p < 8; ++p) {
    float4 u = *(const float4*)(xbp + (long)(o * 8 + p) * D_ + t * 4);
    acc.x += u.x; acc.y += u.y; acc.z += u.z; acc.w += u.w;
  }
  float4 r = {acc.x * (1.f / BS), acc.y * (1.f / BS), acc.z * (1.f / BS), acc.w * (1.f / BS)};
  *(float4*)(xb + (long)o * D_ + t * 4) = r;
}

// ---------------- q_blk / k_blk ----------------
__global__ __launch_bounds__(256) void qkblk2_kernel(const float* __restrict__ xb,
    const float* __restrict__ Wq, const float* __restrict__ bq,
    const float* __restrict__ Wk, const float* __restrict__ bk,
    float* __restrict__ qb, float* __restrict__ kb) {
  int m = blockIdx.x >> 5, ct = blockIdx.x & 31;
  const float* W  = m ? Wk : Wq;
  const float* bi = m ? bk : bq;
  float* out      = m ? kb : qb;
  __shared__ float As[64][132];
  __shared__ float Ws[32][132];
  int t = threadIdx.x;
  int col = t & 31, rg = t >> 5;
  float acc[8];
#pragma unroll
  for (int i = 0; i < 8; ++i) acc[i] = 0.f;
  int srow = t >> 2, sks = (t & 3) * 32;
  for (int kc = 0; kc < 8; ++kc) {
    int k0 = kc * 128;
    __syncthreads();
#pragma unroll
    for (int j = 0; j < 8; ++j)
      *(float4*)&As[srow][sks + j * 4] = *(const float4*)(xb + (long)srow * D_ + k0 + sks + j * 4);
    if (t < 128) {
      int c = t >> 2, ks = (t & 3) * 32;
#pragma unroll
      for (int j = 0; j < 8; ++j)
        *(float4*)&Ws[c][ks + j * 4] =
            *(const float4*)(W + (long)(ct * 32 + c) * D_ + k0 + ks + j * 4);
    }
    __syncthreads();
#pragma unroll
    for (int k4 = 0; k4 < 32; ++k4) {
      float4 wv = *(const float4*)&Ws[col][k4 * 4];
#pragma unroll
      for (int i = 0; i < 8; ++i) {
        float4 av = *(const float4*)&As[rg * 8 + i][k4 * 4];
        acc[i] += av.x * wv.x + av.y * wv.y + av.z * wv.z + av.w * wv.w;
      }
    }
  }
  float bv = bi[ct * 32 + col];
#pragma unroll
  for (int i = 0; i < 8; ++i)
    out[(long)(rg * 8 + i) * D_ + ct * 32 + col] = acc[i] + bv;
}

// ---------------- logits ----------------
__global__ __launch_bounds__(256) void logits_kernel(const float* __restrict__ qb,
                                                     const float* __restrict__ kb,
                                                     float* __restrict__ lg) {
  int idx = blockIdx.x * 4 + (threadIdx.x >> 6);
  int b = idx >> 8, n = (idx >> 4) & 15, m = idx & 15;
  int lane = threadIdx.x & 63;
  float acc = 0.f;
  const float* qp = qb + (b * 16 + n) * D_ + lane;
  const float* kp = kb + (b * 16 + m) * D_ + lane;
#pragma unroll
  for (int kk = 0; kk < 16; ++kk) acc += qp[kk * 64] * kp[kk * 64];
#pragma unroll
  for (int mm = 1; mm < 64; mm <<= 1) acc += __shfl_xor(acc, mm);
  if (lane == 0) lg[idx] = acc * (1.f / 32.f);
}

// ---------------- Sinkhorn + argmax ----------------
__global__ __launch_bounds__(256) void sinkhorn_kernel(const float* __restrict__ lg,
                                                       int* __restrict__ perm) {
  int b = blockIdx.x;
  __shared__ float L[16][17];
  int t = threadIdx.x;
  int n = t >> 4, m = t & 15;
  L[n][m] = lg[b * 256 + t];
  __syncthreads();
  for (int it = 0; it < 5; ++it) {
    float mx = -3e38f;
#pragma unroll
    for (int i = 0; i < 16; ++i) mx = fmaxf(mx, L[n][i]);
    float sm = 0.f;
#pragma unroll
    for (int i = 0; i < 16; ++i) sm += expf(L[n][i] - mx);
    float lse = mx + logf(sm);
    __syncthreads();
    L[n][m] -= lse;
    __syncthreads();
    mx = -3e38f;
#pragma unroll
    for (int i = 0; i < 16; ++i) mx = fmaxf(mx, L[i][m]);
    sm = 0.f;
#pragma unroll
    for (int i = 0; i < 16; ++i) sm += expf(L[i][m] - mx);
    lse = mx + logf(sm);
    __syncthreads();
    L[n][m] -= lse;
    __syncthreads();
  }
  if (t < 16) {
    float best = -3e38f; int bi = 0;
#pragma unroll
    for (int i = 0; i < 16; ++i) {
      float v = L[t][i];
      if (v > best) { best = v; bi = i; }
    }
    perm[b * 16 + t] = bi;
  }
}

// ---------------- merged weight split: 4 matrices -> hi/lo bf16 ----------------
__global__ __launch_bounds__(256) void wsplit_kernel(
    const float* __restrict__ Wq, const float* __restrict__ Wk,
    const float* __restrict__ Wv, const float* __restrict__ Wo,
    u16* __restrict__ whi, u16* __restrict__ wlo,
    u16* __restrict__ wohi, u16* __restrict__ wolo) {
  const size_t NW = (size_t)D_ * D_;
  int z = blockIdx.y;
  const float* src = (z == 0) ? Wq : (z == 1) ? Wk : (z == 2) ? Wv : Wo;
  u16* dh = (z < 3) ? (whi + (size_t)z * NW) : wohi;
  u16* dl = (z < 3) ? (wlo + (size_t)z * NW) : wolo;
  long i = (long)blockIdx.x * 256 + threadIdx.x;
  float4 v = ((const float4*)src)[i];
  ushort4 h, l;
  h.x = f2bfu(v.x); l.x = f2bfu(v.x - bfu2f(h.x));
  h.y = f2bfu(v.y); l.y = f2bfu(v.y - bfu2f(h.y));
  h.z = f2bfu(v.z); l.z = f2bfu(v.z - bfu2f(h.z));
  h.w = f2bfu(v.w); l.w = f2bfu(v.w - bfu2f(h.w));
  ((ushort4*)dh)[i] = h;
  ((ushort4*)dl)[i] = l;
}

// ---------------- QKV GEMM v6: overlap staging with MFMA, single 32KB buffer -----
// Per k-step: read frags(cur tile)->regs ; barrier ; issue gld(next tile) ; MFMA
// (loads fly under the MFMA cluster) ; barrier (vmcnt drain now lands ~233cy after
// issue, not 0). Same LDS/occupancy as the proven round-3 body; XCD mapping kept.
__global__ __launch_bounds__(256, 3) void gemm_qkv_kernel(
    const u16* __restrict__ xhi, const u16* __restrict__ xlo,
    const u16* __restrict__ whi, const u16* __restrict__ wlo,
    const float* __restrict__ bq, const float* __restrict__ bk, const float* __restrict__ bv,
    u16* __restrict__ Qbf, u16* __restrict__ Khi, u16* __restrict__ Klo,
    u16* __restrict__ Vbf, const int* __restrict__ perm, int grp) {
  int hw = blockIdx.x;
  int xcd = hw & 7, idx = hw >> 3;       // idx 0..191
  int yl = idx / 24, rem = idx - yl * 24;
  int z = rem >> 3, xt = rem & 7;
  int y = xcd * 8 + yl;                  // 0..63
  const u16* Wh = whi + (size_t)z * (D_ * D_);
  const u16* Wl = wlo + (size_t)z * (D_ * D_);
  const float* bi = (z == 0) ? bq : (z == 1) ? bk : bv;
  int g = y >> 5, st = y & 31;
  int b = grp * 2 + g;
  int col0 = xt * 128;
  int n = st >> 1;
  int sb = perm[b * NB + n];
  const long a_stride = (long)B_ * D_;
  long a_off = ((long)(sb * BS + (st & 1) * 128) * B_ + b) * D_;
  const u16* Ahg = xhi + a_off;
  const u16* Alg = xlo + a_off;

  __shared__ u16 Ash[4096], Asl[4096], Bsh[4096], Bsl[4096];
  int t = threadIdx.x;
  int w = t >> 6, lane = t & 63, quad = lane >> 4, l15 = lane & 15;
  int wm = w >> 1, wn = w & 1;
  f32x4 acc[4][4];
#pragma unroll
  for (int i = 0; i < 4; ++i)
#pragma unroll
    for (int j = 0; j < 4; ++j) acc[i][j] = {0.f, 0.f, 0.f, 0.f};

  int ch0 = t, ch1 = t + 256;
  int r0 = ch0 >> 2, kc0 = ((ch0 & 3) ^ ((ch0 >> 3) & 3)) * 8;
  int r1 = ch1 >> 2, kc1 = ((ch1 & 3) ^ ((ch1 >> 3) & 3)) * 8;
  int cswz = (quad ^ ((l15 >> 1) & 3)) * 8;

#define QKV_STAGE(K0)                                                          \
  do {                                                                         \
    gld_lds16(Ahg + (long)r0 * a_stride + (K0) + kc0, Ash + ch0 * 8);          \
    gld_lds16(Ahg + (long)r1 * a_stride + (K0) + kc1, Ash + ch1 * 8);          \
    gld_lds16(Alg + (long)r0 * a_stride + (K0) + kc0, Asl + ch0 * 8);          \
    gld_lds16(Alg + (long)r1 * a_stride + (K0) + kc1, Asl + ch1 * 8);          \
    gld_lds16(Wh + (long)(col0 + r0) * D_ + (K0) + kc0, Bsh + ch0 * 8);        \
    gld_lds16(Wh + (long)(col0 + r1) * D_ + (K0) + kc1, Bsh + ch1 * 8);        \
    gld_lds16(Wl + (long)(col0 + r0) * D_ + (K0) + kc0, Bsl + ch0 * 8);        \
    gld_lds16(Wl + (long)(col0 + r1) * D_ + (K0) + kc1, Bsl + ch1 * 8);        \
  } while (0)

#define QKV_READ                                                               \
  do {                                                                         \
    _Pragma("unroll") for (int i = 0; i < 4; ++i) {                            \
      ah[i] = *(const bf16x8*)(Ash + (wm * 64 + i * 16 + l15) * 32 + cswz);    \
      al[i] = *(const bf16x8*)(Asl + (wm * 64 + i * 16 + l15) * 32 + cswz);    \
    }                                                                          \
    _Pragma("unroll") for (int j = 0; j < 4; ++j) {                            \
      bh[j] = *(const bf16x8*)(Bsh + (wn * 64 + j * 16 + l15) * 32 + cswz);    \
      bl[j] = *(const bf16x8*)(Bsl + (wn * 64 + j * 16 + l15) * 32 + cswz);    \
    }                                                                          \
  } while (0)

#define QKV_MFMA                                                               \
  do {                                                                         \
    _Pragma("unroll") for (int i = 0; i < 4; ++i)                              \
      _Pragma("unroll") for (int j = 0; j < 4; ++j) {                          \
        acc[i][j] = __builtin_amdgcn_mfma_f32_16x16x32_bf16(al[i], bh[j], acc[i][j], 0, 0, 0); \
        acc[i][j] = __builtin_amdgcn_mfma_f32_16x16x32_bf16(ah[i], bl[j], acc[i][j], 0, 0, 0); \
        acc[i][j] = __builtin_amdgcn_mfma_f32_16x16x32_bf16(ah[i], bh[j], acc[i][j], 0, 0, 0); \
      }                                                                        \
  } while (0)

  QKV_STAGE(0);
  __syncthreads();
#pragma unroll 1
  for (int kt = 0; kt < 31; ++kt) {
    bf16x8 ah[4], al[4], bh[4], bl[4];
    QKV_READ;
    __syncthreads();                 // all waves done reading this tile
    QKV_STAGE((kt + 1) * 32);        // overwrite in-flight under MFMA
    QKV_MFMA;
    __syncthreads();                 // vmcnt drain after ~233cy of MFMA
  }
  {
    bf16x8 ah[4], al[4], bh[4], bl[4];
    QKV_READ;
    QKV_MFMA;
  }
#undef QKV_STAGE
#undef QKV_READ
#undef QKV_MFMA

#pragma unroll
  for (int j = 0; j < 4; ++j) {
    float bvv = bi[col0 + wn * 64 + j * 16 + l15];
#pragma unroll
    for (int i = 0; i < 4; ++i) {
      int row = wm * 64 + i * 16 + quad * 4;
      long base = ((long)g * S_ + st * 128 + row) * D_ + col0 + wn * 64 + j * 16 + l15;
#pragma unroll
      for (int r = 0; r < 4; ++r) {
        float val = acc[i][j][r] + bvv;
        long a = base + (long)r * D_;
        if (z == 0) {
          Qbf[a] = f2bfu(val * 0.125f);
        } else if (z == 1) {
          u16 hh = f2bfu(val);
          Khi[a] = hh;
          Klo[a] = f2bfu(val - bfu2f(hh));
        } else {
          Vbf[a] = f2bfu(val);
        }
      }
    }
  }
}

// ---------------- out GEMM: same overlap restructure, XCD-aware, grid 512 --------
__global__ __launch_bounds__(256, 3) void gemm_out_kernel(
    const u16* __restrict__ Ahi, const u16* __restrict__ Alo,
    const u16* __restrict__ wohi, const u16* __restrict__ wolo,
    const float* __restrict__ bo, float* __restrict__ out, int grp) {
  int hw = blockIdx.x;
  int xcd = hw & 7, idx = hw >> 3;       // idx 0..63
  int yl = idx >> 3, xt = idx & 7;
  int y = xcd * 8 + yl;                  // 0..63
  int g = y >> 5, st = y & 31;
  int b = grp * 2 + g;
  int col0 = xt * 128;
  long a_off = ((long)g * S_ + st * 128) * D_;
  const u16* Ah = Ahi + a_off;
  const u16* Al = Alo + a_off;
  float* cbase = out + ((long)(st * 128) * B_ + b) * D_;
  const long c_stride = (long)B_ * D_;

  __shared__ u16 Ash[4096], Asl[4096], Bsh[4096], Bsl[4096];
  int t = threadIdx.x;
  int w = t >> 6, lane = t & 63, quad = lane >> 4, l15 = lane & 15;
  int wm = w >> 1, wn = w & 1;
  f32x4 acc[4][4];
#pragma unroll
  for (int i = 0; i < 4; ++i)
#pragma unroll
    for (int j = 0; j < 4; ++j) acc[i][j] = {0.f, 0.f, 0.f, 0.f};

  int ch0 = t, ch1 = t + 256;
  int r0 = ch0 >> 2, kc0 = ((ch0 & 3) ^ ((ch0 >> 3) & 3)) * 8;
  int r1 = ch1 >> 2, kc1 = ((ch1 & 3) ^ ((ch1 >> 3) & 3)) * 8;
  int cswz = (quad ^ ((l15 >> 1) & 3)) * 8;

#define OUT_STAGE(K0)                                                          \
  do {                                                                         \
    gld_lds16(Ah + (long)r0 * D_ + (K0) + kc0, Ash + ch0 * 8);                 \
    gld_lds16(Ah + (long)r1 * D_ + (K0) + kc1, Ash + ch1 * 8);                 \
    gld_lds16(Al + (long)r0 * D_ + (K0) + kc0, Asl + ch0 * 8);                 \
    gld_lds16(Al + (long)r1 * D_ + (K0) + kc1, Asl + ch1 * 8);                 \
    gld_lds16(wohi + (long)(col0 + r0) * D_ + (K0) + kc0, Bsh + ch0 * 8);      \
    gld_lds16(wohi + (long)(col0 + r1) * D_ + (K0) + kc1, Bsh + ch1 * 8);      \
    gld_lds16(wolo + (long)(col0 + r0) * D_ + (K0) + kc0, Bsl + ch0 * 8);      \
    gld_lds16(wolo + (long)(col0 + r1) * D_ + (K0) + kc1, Bsl + ch1 * 8);      \
  } while (0)

#define OUT_READ                                                               \
  do {                                                                         \
    _Pragma("unroll") for (int i = 0; i < 4; ++i) {                            \
      ah[i] = *(const bf16x8*)(Ash + (wm * 64 + i * 16 + l15) * 32 + cswz);    \
      al[i] = *(const bf16x8*)(Asl + (wm * 64 + i * 16 + l15) * 32 + cswz);    \
    }                                                                          \
    _Pragma("unroll") for (int j = 0; j < 4; ++j) {                            \
      bh[j] = *(const bf16x8*)(Bsh + (wn * 64 + j * 16 + l15) * 32 + cswz);    \
      bl[j] = *(const bf16x8*)(Bsl + (wn * 64 + j * 16 + l15) * 32 + cswz);    \
    }                                                                          \
  } while (0)

#define OUT_MFMA                                                               \
  do {                                                                         \
    _Pragma("unroll") for (int i = 0; i < 4; ++i)                              \
      _Pragma("unroll") for (int j = 0; j < 4; ++j) {                          \
        acc[i][j] = __builtin_amdgcn_mfma_f32_16x16x32_bf16(al[i], bh[j], acc[i][j], 0, 0, 0); \
        acc[i][j] = __builtin_amdgcn_mfma_f32_16x16x32_bf16(ah[i], bl[j], acc[i][j], 0, 0, 0); \
        acc[i][j] = __builtin_amdgcn_mfma_f32_16x16x32_bf16(ah[i], bh[j], acc[i][j], 0, 0, 0); \
      }                                                                        \
  } while (0)

  OUT_STAGE(0);
  __syncthreads();
#pragma unroll 1
  for (int kt = 0; kt < 31; ++kt) {
    bf16x8 ah[4], al[4], bh[4], bl[4];
    OUT_READ;
    __syncthreads();
    OUT_STAGE((kt + 1) * 32);
    OUT_MFMA;
    __syncthreads();
  }
  {
    bf16x8 ah[4], al[4], bh[4], bl[4];
    OUT_READ;
    OUT_MFMA;
  }
#undef OUT_STAGE
#undef OUT_READ
#undef OUT_MFMA

#pragma unroll
  for (int j = 0; j < 4; ++j) {
    float bvv = bo[col0 + wn * 64 + j * 16 + l15];
#pragma unroll
    for (int i = 0; i < 4; ++i) {
      int row = wm * 64 + i * 16 + quad * 4;
      long base = (long)row * c_stride + col0 + wn * 64 + j * 16 + l15;
#pragma unroll
      for (int r = 0; r < 4; ++r)
        cbase[base + (long)r * c_stride] = acc[i][j][r] + bvv;
    }
  }
}

// ---------------- block-local attention, MFMA flash, bf16 inputs ----------------
__global__ __launch_bounds__(256, 2) void attn_mfma_kernel(
    const u16* __restrict__ Qbf, const u16* __restrict__ KhiG, const u16* __restrict__ KloG,
    const u16* __restrict__ Vbf, u16* __restrict__ aohi, u16* __restrict__ aolo) {
  int g = blockIdx.x >> 8;
  int n = (blockIdx.x >> 4) & 15, h = blockIdx.x & 15;
  long rbase = (long)g * S_ + n * BS;
  int t = threadIdx.x;
  int w = t >> 6, lane = t & 63, quad = lane >> 4, l15 = lane & 15;

  __shared__ __attribute__((aligned(16))) u16 Khi[64][72];
  __shared__ __attribute__((aligned(16))) u16 Klo[64][72];
  __shared__ __attribute__((aligned(16))) u16 Vt[64][72];   // transposed: [d][key]
  __shared__ __attribute__((aligned(16))) u16 Pw[4][64][72];

  bf16x8 vones;
  {
    u16x8 uo;
#pragma unroll
    for (int e = 0; e < 8; ++e) uo[e] = 0x3F80u;  // bf16 1.0
    vones = u2b16(uo);
  }

  bf16x8 qf[4][2];
#pragma unroll
  for (int i = 0; i < 4; ++i)
#pragma unroll
    for (int ks = 0; ks < 2; ++ks)
      qf[i][ks] = u2b16(*(const u16x8*)(Qbf +
          (rbase + w * 64 + i * 16 + l15) * (long)D_ + h * HD + ks * 32 + quad * 8));

  f32x4 acc[4][4];
  f32x4 accl[4];
  float m[4][4];
#pragma unroll
  for (int i = 0; i < 4; ++i) {
    accl[i] = {0.f, 0.f, 0.f, 0.f};
#pragma unroll
    for (int j = 0; j < 4; ++j) {
      acc[i][j] = {0.f, 0.f, 0.f, 0.f};
      m[i][j] = -3e38f;
    }
  }

  int skey = t >> 2, sd0 = (t & 3) * 16;

#pragma unroll 1
  for (int c = 0; c < 4; ++c) {
    __syncthreads();
    {
      long roff = (rbase + c * 64 + skey) * (long)D_ + h * HD + sd0;
      u16x8 h0 = *(const u16x8*)(KhiG + roff);
      u16x8 h1 = *(const u16x8*)(KhiG + roff + 8);
      u16x8 l0 = *(const u16x8*)(KloG + roff);
      u16x8 l1 = *(const u16x8*)(KloG + roff + 8);
      *(u16x8*)&Khi[skey][sd0] = h0;
      *(u16x8*)&Khi[skey][sd0 + 8] = h1;
      *(u16x8*)&Klo[skey][sd0] = l0;
      *(u16x8*)&Klo[skey][sd0 + 8] = l1;
      u16x8 v0 = *(const u16x8*)(Vbf + roff);
      u16x8 v1 = *(const u16x8*)(Vbf + roff + 8);
#pragma unroll
      for (int e = 0; e < 8; ++e) {
        Vt[sd0 + e][skey] = v0[e];
        Vt[sd0 + 8 + e][skey] = v1[e];
      }
    }
    __syncthreads();

    f32x4 s[4][4];
#pragma unroll
    for (int i = 0; i < 4; ++i)
#pragma unroll
      for (int j = 0; j < 4; ++j) s[i][j] = {0.f, 0.f, 0.f, 0.f};
#pragma unroll
    for (int ks = 0; ks < 2; ++ks)
#pragma unroll
      for (int j = 0; j < 4; ++j) {
        bf16x8 kh = *(const bf16x8*)&Khi[j * 16 + l15][ks * 32 + quad * 8];
        bf16x8 kl = *(const bf16x8*)&Klo[j * 16 + l15][ks * 32 + quad * 8];
#pragma unroll
        for (int i = 0; i < 4; ++i) {
          s[i][j] = __builtin_amdgcn_mfma_f32_16x16x32_bf16(qf[i][ks], kl, s[i][j], 0, 0, 0);
          s[i][j] = __builtin_amdgcn_mfma_f32_16x16x32_bf16(qf[i][ks], kh, s[i][j], 0, 0, 0);
        }
      }

#pragma unroll
    for (int i = 0; i < 4; ++i)
#pragma unroll
      for (int r = 0; r < 4; ++r) {
        float mc = fmaxf(fmaxf(s[i][0][r], s[i][1][r]), fmaxf(s[i][2][r], s[i][3][r]));
#pragma unroll
        for (int mk = 1; mk < 16; mk <<= 1) mc = fmaxf(mc, __shfl_xor(mc, mk));
        float mn = fmaxf(m[i][r], mc);
        float sc = __expf(m[i][r] - mn);
        m[i][r] = mn;
#pragma unroll
        for (int j = 0; j < 4; ++j) {
          float p = __expf(s[i][j][r] - mn);
          Pw[w][i * 16 + quad * 4 + r][j * 16 + l15] = f2bfu(p);
        }
        accl[i][r] *= sc;
#pragma unroll
        for (int jd = 0; jd < 4; ++jd) acc[i][jd][r] *= sc;
      }
    __syncthreads();

#pragma unroll
    for (int ks = 0; ks < 2; ++ks) {
      bf16x8 pa[4], vb[4];
#pragma unroll
      for (int i = 0; i < 4; ++i)
        pa[i] = *(const bf16x8*)&Pw[w][i * 16 + l15][ks * 32 + quad * 8];
#pragma unroll
      for (int jd = 0; jd < 4; ++jd)
        vb[jd] = *(const bf16x8*)&Vt[jd * 16 + l15][ks * 32 + quad * 8];
#pragma unroll
      for (int i = 0; i < 4; ++i) {
#pragma unroll
        for (int jd = 0; jd < 4; ++jd)
          acc[i][jd] = __builtin_amdgcn_mfma_f32_16x16x32_bf16(pa[i], vb[jd], acc[i][jd], 0, 0, 0);
        accl[i] = __builtin_amdgcn_mfma_f32_16x16x32_bf16(pa[i], vones, accl[i], 0, 0, 0);
      }
    }
  }

#pragma unroll
  for (int i = 0; i < 4; ++i) {
    float il[4];
#pragma unroll
    for (int r = 0; r < 4; ++r) il[r] = 1.f / accl[i][r];
#pragma unroll
    for (int jd = 0; jd < 4; ++jd)
#pragma unroll
      for (int r = 0; r < 4; ++r) {
        float f = acc[i][jd][r] * il[r];
        u16 hh = f2bfu(f);
        u16 ll = f2bfu(f - bfu2f(hh));
        long addr = (rbase + w * 64 + i * 16 + quad * 4 + r) * (long)D_ + h * HD + jd * 16 + l15;
        aohi[addr] = hh;
        aolo[addr] = ll;
      }
  }
}

// ================= Tier C fallback (proven fp32 path) =================
__global__ __launch_bounds__(256, 2) void gemm_f32_kernel(
    const float* __restrict__ A0,
    const float* __restrict__ W0, const float* __restrict__ W1, const float* __restrict__ W2,
    const float* __restrict__ bi0, const float* __restrict__ bi1, const float* __restrict__ bi2,
    float* __restrict__ O0, float* __restrict__ O1, float* __restrict__ O2,
    const int* __restrict__ perm, int b, int mode) {
  int z = blockIdx.z;
  const float* W  = (z == 0) ? W0 : (z == 1 ? W1 : W2);
  const float* bi = (z == 0) ? bi0 : (z == 1 ? bi1 : bi2);
  float* C        = (z == 0) ? O0 : (z == 1 ? O1 : O2);
  int st = blockIdx.y;
  int col0 = blockIdx.x * 128;
  const float* abase; float* cbase; long a_stride, c_stride;
  if (mode == 0) {
    int n = st >> 1;
    int sb = perm[b * NB + n];
    long a_row0 = (long)sb * BS + (st & 1) * 128;
    abase = A0 + (a_row0 * B_ + b) * D_;
    a_stride = (long)B_ * D_;
    cbase = C + (long)(st * 128) * D_;
    c_stride = D_;
  } else {
    abase = A0 + (long)(st * 128) * D_;
    a_stride = D_;
    cbase = C + ((long)(st * 128) * B_ + b) * D_;
    c_stride = (long)B_ * D_;
  }
  __shared__ float As[16][132];
  __shared__ float Bs[16][132];
  int t = threadIdx.x;
  int lr = t >> 1, kq = (t & 1) * 8;
  int m0 = (t >> 4) * 8, n0 = (t & 15) * 8;
  const float* aptr = abase + (long)lr * a_stride + kq;
  const float* bptr = W + (long)(col0 + lr) * D_ + kq;
  float acc[8][8];
#pragma unroll
  for (int i = 0; i < 8; ++i)
#pragma unroll
    for (int j = 0; j < 8; ++j) acc[i][j] = 0.f;
  for (int kt = 0; kt < D_ / 16; ++kt) {
    float4 av0 = *(const float4*)(aptr);
    float4 av1 = *(const float4*)(aptr + 4);
    float4 bv0 = *(const float4*)(bptr);
    float4 bv1 = *(const float4*)(bptr + 4);
    aptr += 16; bptr += 16;
    __syncthreads();
    As[kq + 0][lr] = av0.x; As[kq + 1][lr] = av0.y;
    As[kq + 2][lr] = av0.z; As[kq + 3][lr] = av0.w;
    As[kq + 4][lr] = av1.x; As[kq + 5][lr] = av1.y;
    As[kq + 6][lr] = av1.z; As[kq + 7][lr] = av1.w;
    Bs[kq + 0][lr] = bv0.x; Bs[kq + 1][lr] = bv0.y;
    Bs[kq + 2][lr] = bv0.z; Bs[kq + 3][lr] = bv0.w;
    Bs[kq + 4][lr] = bv1.x; Bs[kq + 5][lr] = bv1.y;
    Bs[kq + 6][lr] = bv1.z; Bs[kq + 7][lr] = bv1.w;
    __syncthreads();
#pragma unroll
    for (int k = 0; k < 16; ++k) {
      float4 a0 = *(const float4*)&As[k][m0];
      float4 a1 = *(const float4*)&As[k][m0 + 4];
      float4 b0 = *(const float4*)&Bs[k][n0];
      float4 b1 = *(const float4*)&Bs[k][n0 + 4];
      float aa[8] = {a0.x, a0.y, a0.z, a0.w, a1.x, a1.y, a1.z, a1.w};
      float bb[8] = {b0.x, b0.y, b0.z, b0.w, b1.x, b1.y, b1.z, b1.w};
#pragma unroll
      for (int i = 0; i < 8; ++i)
#pragma unroll
        for (int j = 0; j < 8; ++j) acc[i][j] += aa[i] * bb[j];
    }
  }
  float bb[8];
#pragma unroll
  for (int j = 0; j < 8; ++j) bb[j] = bi[col0 + n0 + j];
#pragma unroll
  for (int i = 0; i < 8; ++i) {
    float* cp = cbase + (long)(m0 + i) * c_stride + col0 + n0;
    float4 c0 = {acc[i][0] + bb[0], acc[i][1] + bb[1], acc[i][2] + bb[2], acc[i][3] + bb[3]};
    float4 c1 = {acc[i][4] + bb[4], acc[i][5] + bb[5], acc[i][6] + bb[6], acc[i][7] + bb[7]};
    *(float4*)(cp) = c0;
    *(float4*)(cp + 4) = c1;
  }
}

__global__ __launch_bounds__(256, 2) void attn_f32_kernel(
    float* __restrict__ Q, const float* __restrict__ K, const float* __restrict__ V) {
  int n = blockIdx.x >> 4, h = blockIdx.x & 15;
  int t = threadIdx.x;
  __shared__ float Kc[64][68];
  __shared__ float Vc[64][68];
  float4 qv[16];
  const float* qrow = Q + ((long)(n * BS) + t) * D_ + h * HD;
#pragma unroll
  for (int e = 0; e < 16; ++e) qv[e] = *(const float4*)(qrow + e * 4);
  float m = -3e38f, l = 0.f;
  float4 o4[16];
#pragma unroll
  for (int e = 0; e < 16; ++e) o4[e] = {0.f, 0.f, 0.f, 0.f};
  int sj = t >> 2, se = (t & 3) * 16;
  for (int c = 0; c < 4; ++c) {
    __syncthreads();
    const float* kp = K + ((long)(n * BS + c * 64 + sj)) * D_ + h * HD + se;
    const float* vp = V + ((long)(n * BS + c * 64 + sj)) * D_ + h * HD + se;
#pragma unroll
    for (int i = 0; i < 4; ++i) {
      *(float4*)&Kc[sj][se + i * 4] = *(const float4*)(kp + i * 4);
      *(float4*)&Vc[sj][se + i * 4] = *(const float4*)(vp + i * 4);
    }
    __syncthreads();
    for (int j = 0; j < 64; ++j) {
      float s = 0.f;
#pragma unroll
      for (int e = 0; e < 16; ++e) {
        float4 kv = *(const float4*)&Kc[j][e * 4];
        s += qv[e].x * kv.x + qv[e].y * kv.y + qv[e].z * kv.z + qv[e].w * kv.w;
      }
      s *= 0.125f;
      if (s > m) {
        float sc = __expf(m - s);
        l *= sc;
#pragma unroll
        for (int e = 0; e < 16; ++e) {
          o4[e].x *= sc; o4[e].y *= sc; o4[e].z *= sc; o4[e].w *= sc;
        }
        m = s;
      }
      float p = __expf(s - m);
      l += p;
#pragma unroll
      for (int e = 0; e < 16; ++e) {
        float4 vv = *(const float4*)&Vc[j][e * 4];
        o4[e].x += p * vv.x; o4[e].y += p * vv.y;
        o4[e].z += p * vv.z; o4[e].w += p * vv.w;
      }
    }
  }
  float inv = 1.f / l;
  float* orow = Q + ((long)(n * BS) + t) * D_ + h * HD;
#pragma unroll
  for (int e = 0; e < 16; ++e) {
    float4 ov = {o4[e].x * inv, o4[e].y * inv, o4[e].z * inv, o4[e].w * inv};
    *(float4*)(orow + e * 4) = ov;
  }
}

// ---------------- launch ----------------
extern "C" void kernel_launch(void* const* d_in, const int* in_sizes, int n_in,
                              void* d_out, int out_size, void* d_ws, size_t ws_size,
                              hipStream_t stream) {
  (void)in_sizes; (void)n_in; (void)out_size;
  const float* x  = (const float*)d_in[0];
  const float* Wq = (const float*)d_in[1];
  const float* bq = (const float*)d_in[2];
  const float* Wk = (const float*)d_in[3];
  const float* bk = (const float*)d_in[4];
  const float* Wv = (const float*)d_in[5];
  const float* bv = (const float*)d_in[6];
  const float* Wo = (const float*)d_in[7];
  const float* bo = (const float*)d_in[8];
  float* out = (float*)d_out;
  char* ws = (char*)d_ws;

  // small scratch (1 MB region)
  float* xbf  = (float*)(ws);                   // 64x1024
  float* qbf  = (float*)(ws + 262144);
  float* kbf  = (float*)(ws + 524288);
  float* lgf  = (float*)(ws + 786432);
  int*   perm = (int*)(ws + 790528);

  const size_t NW  = (size_t)D_ * D_;           // 1,048,576
  const size_t NG  = (size_t)2 * S_ * D_;       // 8,388,608 elems per 2-batch group
  const size_t NX  = (size_t)S_ * B_ * D_;      // 16,777,216 elems of x
  const size_t SM  = 1 << 20;

  // fast-path layout: total = 152,043,520 B (same proven footprint)
  size_t off = SM;
  u16* whi  = (u16*)(ws + off); off += 3 * NW * 2;
  u16* wlo  = (u16*)(ws + off); off += 3 * NW * 2;
  u16* wohi = (u16*)(ws + off); off += NW * 2;
  u16* wolo = (u16*)(ws + off); off += NW * 2;
  u16* xhi  = (u16*)(ws + off); off += NX * 2;
  u16* xlo  = (u16*)(ws + off); off += NX * 2;
  u16* Qbf  = (u16*)(ws + off); off += NG * 2;
  u16* Khi  = (u16*)(ws + off); off += NG * 2;
  u16* Klo  = (u16*)(ws + off); off += NG * 2;
  u16* Vbf  = (u16*)(ws + off); off += NG * 2;
  const size_t need = off;

  // aliases: attn output reuses Q/V bf16 buffers (dead at that point per-group)
  u16* aohi = Vbf;
  u16* aolo = Qbf;

  // routing partials live in dead Qbf space on the fast path
  float* xbp = (float*)Qbf;   // 512 x 1024 f32 = 2 MB
  if (ws_size >= need) {
    // merged mean + x hi/lo split: one pass over x (same sum order -> same perm)
    mean1split_kernel<<<512, 256, 0, stream>>>(x, xbp, xhi, xlo);
    mean2_kernel<<<64, 256, 0, stream>>>(xbp, xbf);
  } else {
    mean1_kernel<<<512, 256, 0, stream>>>(x, (float*)(ws + SM));
    mean2_kernel<<<64, 256, 0, stream>>>((float*)(ws + SM), xbf);
  }
  qkblk2_kernel<<<64, 256, 0, stream>>>(xbf, Wq, bq, Wk, bk, qbf, kbf);
  logits_kernel<<<256, 256, 0, stream>>>(qbf, kbf, lgf);
  sinkhorn_kernel<<<4, 256, 0, stream>>>(lgf, perm);

  if (ws_size >= need) {
    wsplit_kernel<<<dim3(1024, 4), 256, 0, stream>>>(Wq, Wk, Wv, Wo, whi, wlo, wohi, wolo);
    for (int grp = 0; grp < 2; ++grp) {
      gemm_qkv_kernel<<<1536, 256, 0, stream>>>(
          xhi, xlo, whi, wlo, bq, bk, bv, Qbf, Khi, Klo, Vbf, perm, grp);
      attn_mfma_kernel<<<512, 256, 0, stream>>>(Qbf, Khi, Klo, Vbf, aohi, aolo);
      gemm_out_kernel<<<512, 256, 0, stream>>>(
          aohi, aolo, wohi, wolo, bo, out, grp);
    }
  } else {
    // Tier C: proven fp32 path (49 MB)
    float* Qb = (float*)(ws + 4 * SM);
    float* Kb = Qb + (size_t)S_ * D_;
    float* Vb = Kb + (size_t)S_ * D_;
    for (int b = 0; b < B_; ++b) {
      gemm_f32_kernel<<<dim3(8, 32, 3), 256, 0, stream>>>(
          x, Wq, Wk, Wv, bq, bk, bv, Qb, Kb, Vb, perm, b, 0);
      attn_f32_kernel<<<256, 256, 0, stream>>>(Qb, Kb, Vb);
      gemm_f32_kernel<<<dim3(8, 32, 1), 256, 0, stream>>>(
          Qb, Wo, Wo, Wo, bo, bo, bo, out, out, out, perm, b, 1);
    }
  }
}

// Round 8
// 684.852 us; speedup vs baseline: 1.2204x; 1.0029x over previous
//
#include <hip/hip_runtime.h>
#include <math.h>

typedef unsigned short u16;
typedef __bf16 bf16t;
typedef bf16t bf16x8 __attribute__((ext_vector_type(8)));
typedef u16 u16x8 __attribute__((ext_vector_type(8)));
typedef float f32x4 __attribute__((ext_vector_type(4)));

#define D_ 1024
#define S_ 4096
#define B_ 4
#define NB 16
#define BS 256
#define NH 16
#define HD 64

__device__ __forceinline__ float bfu2f(u16 u) {
  unsigned int x = ((unsigned int)u) << 16;
  float f; __builtin_memcpy(&f, &x, 4); return f;
}
__device__ __forceinline__ u16 f2bfu(float f) {
  unsigned int x; __builtin_memcpy(&x, &f, 4);
  x += 0x7fffu + ((x >> 16) & 1u);   // RNE
  return (u16)(x >> 16);
}
__device__ __forceinline__ bf16x8 u2b16(u16x8 u) {
  bf16x8 r; __builtin_memcpy(&r, &u, 16); return r;
}
__device__ __forceinline__ void gld_lds16(const void* g, void* l) {
  __builtin_amdgcn_global_load_lds((__attribute__((address_space(1))) void*)g,
                                   (__attribute__((address_space(3))) void*)l, 16, 0, 0);
}

// ---------------- block means, two-stage ----------------
// Tier C variant (no split buffers available)
__global__ __launch_bounds__(256) void mean1_kernel(const float* __restrict__ x,
                                                    float* __restrict__ xbp) {
  int bx = blockIdx.x;
  int o = bx >> 3, p = bx & 7;
  int b = o >> 4, n = o & 15;
  int t = threadIdx.x;
  float4 acc = {0.f, 0.f, 0.f, 0.f};
  const float* xp = x + ((long)(n * BS + p * 32) * B_ + b) * D_ + t * 4;
  for (int s = 0; s < 32; ++s) {
    float4 u = *(const float4*)xp;
    acc.x += u.x; acc.y += u.y; acc.z += u.z; acc.w += u.w;
    xp += B_ * D_;
  }
  *(float4*)(xbp + (long)bx * D_ + t * 4) = acc;
}
// fast-path variant: same reads & bit-identical sum order + hi/lo split store
__global__ __launch_bounds__(256) void mean1split_kernel(const float* __restrict__ x,
    float* __restrict__ xbp, u16* __restrict__ xhi, u16* __restrict__ xlo) {
  int bx = blockIdx.x;
  int o = bx >> 3, p = bx & 7;
  int b = o >> 4, n = o & 15;
  int t = threadIdx.x;
  float4 acc = {0.f, 0.f, 0.f, 0.f};
  long base = ((long)(n * BS + p * 32) * B_ + b) * D_ + t * 4;
  const float* xp = x + base;
  long idx = base;
  for (int s = 0; s < 32; ++s) {
    float4 u = *(const float4*)xp;
    acc.x += u.x; acc.y += u.y; acc.z += u.z; acc.w += u.w;
    ushort4 h, l;
    h.x = f2bfu(u.x); l.x = f2bfu(u.x - bfu2f(h.x));
    h.y = f2bfu(u.y); l.y = f2bfu(u.y - bfu2f(h.y));
    h.z = f2bfu(u.z); l.z = f2bfu(u.z - bfu2f(h.z));
    h.w = f2bfu(u.w); l.w = f2bfu(u.w - bfu2f(h.w));
    *(ushort4*)(xhi + idx) = h;
    *(ushort4*)(xlo + idx) = l;
    xp += B_ * D_;
    idx += B_ * D_;
  }
  *(float4*)(xbp + (long)bx * D_ + t * 4) = acc;
}
__global__ __launch_bounds__(256) void mean2_kernel(const float* __restrict__ xbp,
                                                    float* __restrict__ xb) {
  int o = blockIdx.x, t = threadIdx.x;
  float4 acc = {0.f, 0.f, 0.f, 0.f};
#pragma unroll
  for (int p = 0; p < 8; ++p) {
    float4 u = *(const float4*)(xbp + (long)(o * 8 + p) * D_ + t * 4);
    acc.x += u.x; acc.y += u.y; acc.z += u.z; acc.w += u.w;
  }
  float4 r = {acc.x * (1.f / BS), acc.y * (1.f / BS), acc.z * (1.f / BS), acc.w * (1.f / BS)};
  *(float4*)(xb + (long)o * D_ + t * 4) = r;
}

// ---------------- q_blk / k_blk ----------------
__global__ __launch_bounds__(256) void qkblk2_kernel(const float* __restrict__ xb,
    const float* __restrict__ Wq, const float* __restrict__ bq,
    const float* __restrict__ Wk, const float* __restrict__ bk,
    float* __restrict__ qb, float* __restrict__ kb) {
  int m = blockIdx.x >> 5, ct = blockIdx.x & 31;
  const float* W  = m ? Wk : Wq;
  const float* bi = m ? bk : bq;
  float* out      = m ? kb : qb;
  __shared__ float As[64][132];
  __shared__ float Ws[32][132];
  int t = threadIdx.x;
  int col = t & 31, rg = t >> 5;
  float acc[8];
#pragma unroll
  for (int i = 0; i < 8; ++i) acc[i] = 0.f;
  int srow = t >> 2, sks = (t & 3) * 32;
  for (int kc = 0; kc < 8; ++kc) {
    int k0 = kc * 128;
    __syncthreads();
#pragma unroll
    for (int j = 0; j < 8; ++j)
      *(float4*)&As[srow][sks + j * 4] = *(const float4*)(xb + (long)srow * D_ + k0 + sks + j * 4);
    if (t < 128) {
      int c = t >> 2, ks = (t & 3) * 32;
#pragma unroll
      for (int j = 0; j < 8; ++j)
        *(float4*)&Ws[c][ks + j * 4] =
            *(const float4*)(W + (long)(ct * 32 + c) * D_ + k0 + ks + j * 4);
    }
    __syncthreads();
#pragma unroll
    for (int k4 = 0; k4 < 32; ++k4) {
      float4 wv = *(const float4*)&Ws[col][k4 * 4];
#pragma unroll
      for (int i = 0; i < 8; ++i) {
        float4 av = *(const float4*)&As[rg * 8 + i][k4 * 4];
        acc[i] += av.x * wv.x + av.y * wv.y + av.z * wv.z + av.w * wv.w;
      }
    }
  }
  float bv = bi[ct * 32 + col];
#pragma unroll
  for (int i = 0; i < 8; ++i)
    out[(long)(rg * 8 + i) * D_ + ct * 32 + col] = acc[i] + bv;
}

// ---------------- logits ----------------
__global__ __launch_bounds__(256) void logits_kernel(const float* __restrict__ qb,
                                                     const float* __restrict__ kb,
                                                     float* __restrict__ lg) {
  int idx = blockIdx.x * 4 + (threadIdx.x >> 6);
  int b = idx >> 8, n = (idx >> 4) & 15, m = idx & 15;
  int lane = threadIdx.x & 63;
  float acc = 0.f;
  const float* qp = qb + (b * 16 + n) * D_ + lane;
  const float* kp = kb + (b * 16 + m) * D_ + lane;
#pragma unroll
  for (int kk = 0; kk < 16; ++kk) acc += qp[kk * 64] * kp[kk * 64];
#pragma unroll
  for (int mm = 1; mm < 64; mm <<= 1) acc += __shfl_xor(acc, mm);
  if (lane == 0) lg[idx] = acc * (1.f / 32.f);
}

// ---------------- Sinkhorn + argmax ----------------
__global__ __launch_bounds__(256) void sinkhorn_kernel(const float* __restrict__ lg,
                                                       int* __restrict__ perm) {
  int b = blockIdx.x;
  __shared__ float L[16][17];
  int t = threadIdx.x;
  int n = t >> 4, m = t & 15;
  L[n][m] = lg[b * 256 + t];
  __syncthreads();
  for (int it = 0; it < 5; ++it) {
    float mx = -3e38f;
#pragma unroll
    for (int i = 0; i < 16; ++i) mx = fmaxf(mx, L[n][i]);
    float sm = 0.f;
#pragma unroll
    for (int i = 0; i < 16; ++i) sm += expf(L[n][i] - mx);
    float lse = mx + logf(sm);
    __syncthreads();
    L[n][m] -= lse;
    __syncthreads();
    mx = -3e38f;
#pragma unroll
    for (int i = 0; i < 16; ++i) mx = fmaxf(mx, L[i][m]);
    sm = 0.f;
#pragma unroll
    for (int i = 0; i < 16; ++i) sm += expf(L[i][m] - mx);
    lse = mx + logf(sm);
    __syncthreads();
    L[n][m] -= lse;
    __syncthreads();
  }
  if (t < 16) {
    float best = -3e38f; int bi = 0;
#pragma unroll
    for (int i = 0; i < 16; ++i) {
      float v = L[t][i];
      if (v > best) { best = v; bi = i; }
    }
    perm[b * 16 + t] = bi;
  }
}

// ---------------- merged weight split: 4 matrices -> hi/lo bf16 ----------------
__global__ __launch_bounds__(256) void wsplit_kernel(
    const float* __restrict__ Wq, const float* __restrict__ Wk,
    const float* __restrict__ Wv, const float* __restrict__ Wo,
    u16* __restrict__ whi, u16* __restrict__ wlo,
    u16* __restrict__ wohi, u16* __restrict__ wolo) {
  const size_t NW = (size_t)D_ * D_;
  int z = blockIdx.y;
  const float* src = (z == 0) ? Wq : (z == 1) ? Wk : (z == 2) ? Wv : Wo;
  u16* dh = (z < 3) ? (whi + (size_t)z * NW) : wohi;
  u16* dl = (z < 3) ? (wlo + (size_t)z * NW) : wolo;
  long i = (long)blockIdx.x * 256 + threadIdx.x;
  float4 v = ((const float4*)src)[i];
  ushort4 h, l;
  h.x = f2bfu(v.x); l.x = f2bfu(v.x - bfu2f(h.x));
  h.y = f2bfu(v.y); l.y = f2bfu(v.y - bfu2f(h.y));
  h.z = f2bfu(v.z); l.z = f2bfu(v.z - bfu2f(h.z));
  h.w = f2bfu(v.w); l.w = f2bfu(v.w - bfu2f(h.w));
  ((ushort4*)dh)[i] = h;
  ((ushort4*)dl)[i] = l;
}

// ---------------- QKV GEMM v7: counted-vmcnt 2-deep pipeline (T4) ----------------
// 2 LDS buffers. Main loop waits vmcnt(8): only the tile staged TWO K-steps ago
// must have landed; the just-issued tile's 8 loads stay in flight under the MFMA
// cluster. No vmcnt(0) drain until the peeled last iteration.
__global__ __launch_bounds__(256, 2) void gemm_qkv_kernel(
    const u16* __restrict__ xhi, const u16* __restrict__ xlo,
    const u16* __restrict__ whi, const u16* __restrict__ wlo,
    const float* __restrict__ bq, const float* __restrict__ bk, const float* __restrict__ bv,
    u16* __restrict__ Qbf, u16* __restrict__ Khi, u16* __restrict__ Klo,
    u16* __restrict__ Vbf, const int* __restrict__ perm, int grp) {
  int hw = blockIdx.x;
  int xcd = hw & 7, idx = hw >> 3;       // idx 0..191
  int yl = idx / 24, rem = idx - yl * 24;
  int z = rem >> 3, xt = rem & 7;
  int y = xcd * 8 + yl;                  // 0..63
  const u16* Wh = whi + (size_t)z * (D_ * D_);
  const u16* Wl = wlo + (size_t)z * (D_ * D_);
  const float* bi = (z == 0) ? bq : (z == 1) ? bk : bv;
  int g = y >> 5, st = y & 31;
  int b = grp * 2 + g;
  int col0 = xt * 128;
  int n = st >> 1;
  int sb = perm[b * NB + n];
  const long a_stride = (long)B_ * D_;
  long a_off = ((long)(sb * BS + (st & 1) * 128) * B_ + b) * D_;
  const u16* Ahg = xhi + a_off;
  const u16* Alg = xlo + a_off;

  __shared__ __attribute__((aligned(16))) u16 Ash[2][4096], Asl[2][4096],
                                              Bsh[2][4096], Bsl[2][4096];
  int t = threadIdx.x;
  int w = t >> 6, lane = t & 63, quad = lane >> 4, l15 = lane & 15;
  int wm = w >> 1, wn = w & 1;
  f32x4 acc[4][4];
#pragma unroll
  for (int i = 0; i < 4; ++i)
#pragma unroll
    for (int j = 0; j < 4; ++j) acc[i][j] = {0.f, 0.f, 0.f, 0.f};

  int ch0 = t, ch1 = t + 256;
  int r0 = ch0 >> 2, kc0 = ((ch0 & 3) ^ ((ch0 >> 3) & 3)) * 8;
  int r1 = ch1 >> 2, kc1 = ((ch1 & 3) ^ ((ch1 >> 3) & 3)) * 8;
  int cswz = (quad ^ ((l15 >> 1) & 3)) * 8;

#define QKV_STAGE(BUF, K0)                                                     \
  do {                                                                         \
    gld_lds16(Ahg + (long)r0 * a_stride + (K0) + kc0, &Ash[BUF][ch0 * 8]);     \
    gld_lds16(Ahg + (long)r1 * a_stride + (K0) + kc1, &Ash[BUF][ch1 * 8]);     \
    gld_lds16(Alg + (long)r0 * a_stride + (K0) + kc0, &Asl[BUF][ch0 * 8]);     \
    gld_lds16(Alg + (long)r1 * a_stride + (K0) + kc1, &Asl[BUF][ch1 * 8]);     \
    gld_lds16(Wh + (long)(col0 + r0) * D_ + (K0) + kc0, &Bsh[BUF][ch0 * 8]);   \
    gld_lds16(Wh + (long)(col0 + r1) * D_ + (K0) + kc1, &Bsh[BUF][ch1 * 8]);   \
    gld_lds16(Wl + (long)(col0 + r0) * D_ + (K0) + kc0, &Bsl[BUF][ch0 * 8]);   \
    gld_lds16(Wl + (long)(col0 + r1) * D_ + (K0) + kc1, &Bsl[BUF][ch1 * 8]);   \
  } while (0)

#define QKV_READ(BUF)                                                          \
  do {                                                                         \
    _Pragma("unroll") for (int i = 0; i < 4; ++i) {                            \
      ah[i] = *(const bf16x8*)(&Ash[BUF][0] + (wm * 64 + i * 16 + l15) * 32 + cswz); \
      al[i] = *(const bf16x8*)(&Asl[BUF][0] + (wm * 64 + i * 16 + l15) * 32 + cswz); \
    }                                                                          \
    _Pragma("unroll") for (int j = 0; j < 4; ++j) {                            \
      bh[j] = *(const bf16x8*)(&Bsh[BUF][0] + (wn * 64 + j * 16 + l15) * 32 + cswz); \
      bl[j] = *(const bf16x8*)(&Bsl[BUF][0] + (wn * 64 + j * 16 + l15) * 32 + cswz); \
    }                                                                          \
  } while (0)

#define QKV_MFMA                                                               \
  do {                                                                         \
    _Pragma("unroll") for (int i = 0; i < 4; ++i)                              \
      _Pragma("unroll") for (int j = 0; j < 4; ++j) {                          \
        acc[i][j] = __builtin_amdgcn_mfma_f32_16x16x32_bf16(al[i], bh[j], acc[i][j], 0, 0, 0); \
        acc[i][j] = __builtin_amdgcn_mfma_f32_16x16x32_bf16(ah[i], bl[j], acc[i][j], 0, 0, 0); \
        acc[i][j] = __builtin_amdgcn_mfma_f32_16x16x32_bf16(ah[i], bh[j], acc[i][j], 0, 0, 0); \
      }                                                                        \
  } while (0)

  QKV_STAGE(0, 0);
  QKV_STAGE(1, 32);
#pragma unroll 1
  for (int kt = 0; kt < 31; ++kt) {
    bf16x8 ah[4], al[4], bh[4], bl[4];
    asm volatile("s_waitcnt vmcnt(8)" ::: "memory");   // tile kt landed; kt+1 in flight
    __builtin_amdgcn_s_barrier();
    QKV_READ(kt & 1);
    asm volatile("s_waitcnt lgkmcnt(0)" ::: "memory"); // frags in regs for all lanes
    __builtin_amdgcn_s_barrier();                      // all waves done reading buf
    if (kt < 30) QKV_STAGE(kt & 1, (kt + 2) * 32);     // overwrite; flies under MFMA
    QKV_MFMA;
  }
  {
    bf16x8 ah[4], al[4], bh[4], bl[4];
    asm volatile("s_waitcnt vmcnt(0)" ::: "memory");   // final tile (31) drain
    __builtin_amdgcn_s_barrier();
    QKV_READ(1);
    QKV_MFMA;
  }
#undef QKV_STAGE
#undef QKV_READ
#undef QKV_MFMA

#pragma unroll
  for (int j = 0; j < 4; ++j) {
    float bvv = bi[col0 + wn * 64 + j * 16 + l15];
#pragma unroll
    for (int i = 0; i < 4; ++i) {
      int row = wm * 64 + i * 16 + quad * 4;
      long base = ((long)g * S_ + st * 128 + row) * D_ + col0 + wn * 64 + j * 16 + l15;
#pragma unroll
      for (int r = 0; r < 4; ++r) {
        float val = acc[i][j][r] + bvv;
        long a = base + (long)r * D_;
        if (z == 0) {
          Qbf[a] = f2bfu(val * 0.125f);
        } else if (z == 1) {
          u16 hh = f2bfu(val);
          Khi[a] = hh;
          Klo[a] = f2bfu(val - bfu2f(hh));
        } else {
          Vbf[a] = f2bfu(val);
        }
      }
    }
  }
}

// ---------------- out GEMM: counted-vmcnt 2-deep pipeline, XCD-aware ------------
__global__ __launch_bounds__(256, 2) void gemm_out_kernel(
    const u16* __restrict__ Ahi, const u16* __restrict__ Alo,
    const u16* __restrict__ wohi, const u16* __restrict__ wolo,
    const float* __restrict__ bo, float* __restrict__ out, int grp) {
  int hw = blockIdx.x;
  int xcd = hw & 7, idx = hw >> 3;       // idx 0..63
  int yl = idx >> 3, xt = idx & 7;
  int y = xcd * 8 + yl;                  // 0..63
  int g = y >> 5, st = y & 31;
  int b = grp * 2 + g;
  int col0 = xt * 128;
  long a_off = ((long)g * S_ + st * 128) * D_;
  const u16* Ah = Ahi + a_off;
  const u16* Al = Alo + a_off;
  float* cbase = out + ((long)(st * 128) * B_ + b) * D_;
  const long c_stride = (long)B_ * D_;

  __shared__ __attribute__((aligned(16))) u16 Ash[2][4096], Asl[2][4096],
                                              Bsh[2][4096], Bsl[2][4096];
  int t = threadIdx.x;
  int w = t >> 6, lane = t & 63, quad = lane >> 4, l15 = lane & 15;
  int wm = w >> 1, wn = w & 1;
  f32x4 acc[4][4];
#pragma unroll
  for (int i = 0; i < 4; ++i)
#pragma unroll
    for (int j = 0; j < 4; ++j) acc[i][j] = {0.f, 0.f, 0.f, 0.f};

  int ch0 = t, ch1 = t + 256;
  int r0 = ch0 >> 2, kc0 = ((ch0 & 3) ^ ((ch0 >> 3) & 3)) * 8;
  int r1 = ch1 >> 2, kc1 = ((ch1 & 3) ^ ((ch1 >> 3) & 3)) * 8;
  int cswz = (quad ^ ((l15 >> 1) & 3)) * 8;

#define OUT_STAGE(BUF, K0)                                                      \
  do {                                                                          \
    gld_lds16(Ah + (long)r0 * D_ + (K0) + kc0, &Ash[BUF][ch0 * 8]);             \
    gld_lds16(Ah + (long)r1 * D_ + (K0) + kc1, &Ash[BUF][ch1 * 8]);             \
    gld_lds16(Al + (long)r0 * D_ + (K0) + kc0, &Asl[BUF][ch0 * 8]);             \
    gld_lds16(Al + (long)r1 * D_ + (K0) + kc1, &Asl[BUF][ch1 * 8]);             \
    gld_lds16(wohi + (long)(col0 + r0) * D_ + (K0) + kc0, &Bsh[BUF][ch0 * 8]);  \
    gld_lds16(wohi + (long)(col0 + r1) * D_ + (K0) + kc1, &Bsh[BUF][ch1 * 8]);  \
    gld_lds16(wolo + (long)(col0 + r0) * D_ + (K0) + kc0, &Bsl[BUF][ch0 * 8]);  \
    gld_lds16(wolo + (long)(col0 + r1) * D_ + (K0) + kc1, &Bsl[BUF][ch1 * 8]);  \
  } while (0)

#define OUT_READ(BUF)                                                           \
  do {                                                                          \
    _Pragma("unroll") for (int i = 0; i < 4; ++i) {                             \
      ah[i] = *(const bf16x8*)(&Ash[BUF][0] + (wm * 64 + i * 16 + l15) * 32 + cswz); \
      al[i] = *(const bf16x8*)(&Asl[BUF][0] + (wm * 64 + i * 16 + l15) * 32 + cswz); \
    }                                                                           \
    _Pragma("unroll") for (int j = 0; j < 4; ++j) {                             \
      bh[j] = *(const bf16x8*)(&Bsh[BUF][0] + (wn * 64 + j * 16 + l15) * 32 + cswz); \
      bl[j] = *(const bf16x8*)(&Bsl[BUF][0] + (wn * 64 + j * 16 + l15) * 32 + cswz); \
    }                                                                           \
  } while (0)

#define OUT_MFMA                                                                \
  do {                                                                          \
    _Pragma("unroll") for (int i = 0; i < 4; ++i)                               \
      _Pragma("unroll") for (int j = 0; j < 4; ++j) {                           \
        acc[i][j] = __builtin_amdgcn_mfma_f32_16x16x32_bf16(al[i], bh[j], acc[i][j], 0, 0, 0); \
        acc[i][j] = __builtin_amdgcn_mfma_f32_16x16x32_bf16(ah[i], bl[j], acc[i][j], 0, 0, 0); \
        acc[i][j] = __builtin_amdgcn_mfma_f32_16x16x32_bf16(ah[i], bh[j], acc[i][j], 0, 0, 0); \
      }                                                                         \
  } while (0)

  OUT_STAGE(0, 0);
  OUT_STAGE(1, 32);
#pragma unroll 1
  for (int kt = 0; kt < 31; ++kt) {
    bf16x8 ah[4], al[4], bh[4], bl[4];
    asm volatile("s_waitcnt vmcnt(8)" ::: "memory");
    __builtin_amdgcn_s_barrier();
    OUT_READ(kt & 1);
    asm volatile("s_waitcnt lgkmcnt(0)" ::: "memory");
    __builtin_amdgcn_s_barrier();
    if (kt < 30) OUT_STAGE(kt & 1, (kt + 2) * 32);
    OUT_MFMA;
  }
  {
    bf16x8 ah[4], al[4], bh[4], bl[4];
    asm volatile("s_waitcnt vmcnt(0)" ::: "memory");
    __builtin_amdgcn_s_barrier();
    OUT_READ(1);
    OUT_MFMA;
  }
#undef OUT_STAGE
#undef OUT_READ
#undef OUT_MFMA

#pragma unroll
  for (int j = 0; j < 4; ++j) {
    float bvv = bo[col0 + wn * 64 + j * 16 + l15];
#pragma unroll
    for (int i = 0; i < 4; ++i) {
      int row = wm * 64 + i * 16 + quad * 4;
      long base = (long)row * c_stride + col0 + wn * 64 + j * 16 + l15;
#pragma unroll
      for (int r = 0; r < 4; ++r)
        cbase[base + (long)r * c_stride] = acc[i][j][r] + bvv;
    }
  }
}

// ---------------- block-local attention, MFMA flash, bf16 inputs ----------------
__global__ __launch_bounds__(256, 2) void attn_mfma_kernel(
    const u16* __restrict__ Qbf, const u16* __restrict__ KhiG, const u16* __restrict__ KloG,
    const u16* __restrict__ Vbf, u16* __restrict__ aohi, u16* __restrict__ aolo) {
  int g = blockIdx.x >> 8;
  int n = (blockIdx.x >> 4) & 15, h = blockIdx.x & 15;
  long rbase = (long)g * S_ + n * BS;
  int t = threadIdx.x;
  int w = t >> 6, lane = t & 63, quad = lane >> 4, l15 = lane & 15;

  __shared__ __attribute__((aligned(16))) u16 Khi[64][72];
  __shared__ __attribute__((aligned(16))) u16 Klo[64][72];
  __shared__ __attribute__((aligned(16))) u16 Vt[64][72];   // transposed: [d][key]
  __shared__ __attribute__((aligned(16))) u16 Pw[4][64][72];

  bf16x8 vones;
  {
    u16x8 uo;
#pragma unroll
    for (int e = 0; e < 8; ++e) uo[e] = 0x3F80u;  // bf16 1.0
    vones = u2b16(uo);
  }

  bf16x8 qf[4][2];
#pragma unroll
  for (int i = 0; i < 4; ++i)
#pragma unroll
    for (int ks = 0; ks < 2; ++ks)
      qf[i][ks] = u2b16(*(const u16x8*)(Qbf +
          (rbase + w * 64 + i * 16 + l15) * (long)D_ + h * HD + ks * 32 + quad * 8));

  f32x4 acc[4][4];
  f32x4 accl[4];
  float m[4][4];
#pragma unroll
  for (int i = 0; i < 4; ++i) {
    accl[i] = {0.f, 0.f, 0.f, 0.f};
#pragma unroll
    for (int j = 0; j < 4; ++j) {
      acc[i][j] = {0.f, 0.f, 0.f, 0.f};
      m[i][j] = -3e38f;
    }
  }

  int skey = t >> 2, sd0 = (t & 3) * 16;

#pragma unroll 1
  for (int c = 0; c < 4; ++c) {
    __syncthreads();
    {
      long roff = (rbase + c * 64 + skey) * (long)D_ + h * HD + sd0;
      u16x8 h0 = *(const u16x8*)(KhiG + roff);
      u16x8 h1 = *(const u16x8*)(KhiG + roff + 8);
      u16x8 l0 = *(const u16x8*)(KloG + roff);
      u16x8 l1 = *(const u16x8*)(KloG + roff + 8);
      *(u16x8*)&Khi[skey][sd0] = h0;
      *(u16x8*)&Khi[skey][sd0 + 8] = h1;
      *(u16x8*)&Klo[skey][sd0] = l0;
      *(u16x8*)&Klo[skey][sd0 + 8] = l1;
      u16x8 v0 = *(const u16x8*)(Vbf + roff);
      u16x8 v1 = *(const u16x8*)(Vbf + roff + 8);
#pragma unroll
      for (int e = 0; e < 8; ++e) {
        Vt[sd0 + e][skey] = v0[e];
        Vt[sd0 + 8 + e][skey] = v1[e];
      }
    }
    __syncthreads();

    f32x4 s[4][4];
#pragma unroll
    for (int i = 0; i < 4; ++i)
#pragma unroll
      for (int j = 0; j < 4; ++j) s[i][j] = {0.f, 0.f, 0.f, 0.f};
    __builtin_amdgcn_s_setprio(1);
#pragma unroll
    for (int ks = 0; ks < 2; ++ks)
#pragma unroll
      for (int j = 0; j < 4; ++j) {
        bf16x8 kh = *(const bf16x8*)&Khi[j * 16 + l15][ks * 32 + quad * 8];
        bf16x8 kl = *(const bf16x8*)&Klo[j * 16 + l15][ks * 32 + quad * 8];
#pragma unroll
        for (int i = 0; i < 4; ++i) {
          s[i][j] = __builtin_amdgcn_mfma_f32_16x16x32_bf16(qf[i][ks], kl, s[i][j], 0, 0, 0);
          s[i][j] = __builtin_amdgcn_mfma_f32_16x16x32_bf16(qf[i][ks], kh, s[i][j], 0, 0, 0);
        }
      }
    __builtin_amdgcn_s_setprio(0);

#pragma unroll
    for (int i = 0; i < 4; ++i)
#pragma unroll
      for (int r = 0; r < 4; ++r) {
        float mc = fmaxf(fmaxf(s[i][0][r], s[i][1][r]), fmaxf(s[i][2][r], s[i][3][r]));
#pragma unroll
        for (int mk = 1; mk < 16; mk <<= 1) mc = fmaxf(mc, __shfl_xor(mc, mk));
        float mn = fmaxf(m[i][r], mc);
        float sc = __expf(m[i][r] - mn);
        m[i][r] = mn;
#pragma unroll
        for (int j = 0; j < 4; ++j) {
          float p = __expf(s[i][j][r] - mn);
          Pw[w][i * 16 + quad * 4 + r][j * 16 + l15] = f2bfu(p);
        }
        accl[i][r] *= sc;
#pragma unroll
        for (int jd = 0; jd < 4; ++jd) acc[i][jd][r] *= sc;
      }
    __syncthreads();

    __builtin_amdgcn_s_setprio(1);
#pragma unroll
    for (int ks = 0; ks < 2; ++ks) {
      bf16x8 pa[4], vb[4];
#pragma unroll
      for (int i = 0; i < 4; ++i)
        pa[i] = *(const bf16x8*)&Pw[w][i * 16 + l15][ks * 32 + quad * 8];
#pragma unroll
      for (int jd = 0; jd < 4; ++jd)
        vb[jd] = *(const bf16x8*)&Vt[jd * 16 + l15][ks * 32 + quad * 8];
#pragma unroll
      for (int i = 0; i < 4; ++i) {
#pragma unroll
        for (int jd = 0; jd < 4; ++jd)
          acc[i][jd] = __builtin_amdgcn_mfma_f32_16x16x32_bf16(pa[i], vb[jd], acc[i][jd], 0, 0, 0);
        accl[i] = __builtin_amdgcn_mfma_f32_16x16x32_bf16(pa[i], vones, accl[i], 0, 0, 0);
      }
    }
    __builtin_amdgcn_s_setprio(0);
  }

#pragma unroll
  for (int i = 0; i < 4; ++i) {
    float il[4];
#pragma unroll
    for (int r = 0; r < 4; ++r) il[r] = 1.f / accl[i][r];
#pragma unroll
    for (int jd = 0; jd < 4; ++jd)
#pragma unroll
      for (int r = 0; r < 4; ++r) {
        float f = acc[i][jd][r] * il[r];
        u16 hh = f2bfu(f);
        u16 ll = f2bfu(f - bfu2f(hh));
        long addr = (rbase + w * 64 + i * 16 + quad * 4 + r) * (long)D_ + h * HD + jd * 16 + l15;
        aohi[addr] = hh;
        aolo[addr] = ll;
      }
  }
}

// ================= Tier C fallback (proven fp32 path) =================
__global__ __launch_bounds__(256, 2) void gemm_f32_kernel(
    const float* __restrict__ A0,
    const float* __restrict__ W0, const float* __restrict__ W1, const float* __restrict__ W2,
    const float* __restrict__ bi0, const float* __restrict__ bi1, const float* __restrict__ bi2,
    float* __restrict__ O0, float* __restrict__ O1, float* __restrict__ O2,
    const int* __restrict__ perm, int b, int mode) {
  int z = blockIdx.z;
  const float* W  = (z == 0) ? W0 : (z == 1 ? W1 : W2);
  const float* bi = (z == 0) ? bi0 : (z == 1 ? bi1 : bi2);
  float* C        = (z == 0) ? O0 : (z == 1 ? O1 : O2);
  int st = blockIdx.y;
  int col0 = blockIdx.x * 128;
  const float* abase; float* cbase; long a_stride, c_stride;
  if (mode == 0) {
    int n = st >> 1;
    int sb = perm[b * NB + n];
    long a_row0 = (long)sb * BS + (st & 1) * 128;
    abase = A0 + (a_row0 * B_ + b) * D_;
    a_stride = (long)B_ * D_;
    cbase = C + (long)(st * 128) * D_;
    c_stride = D_;
  } else {
    abase = A0 + (long)(st * 128) * D_;
    a_stride = D_;
    cbase = C + ((long)(st * 128) * B_ + b) * D_;
    c_stride = (long)B_ * D_;
  }
  __shared__ float As[16][132];
  __shared__ float Bs[16][132];
  int t = threadIdx.x;
  int lr = t >> 1, kq = (t & 1) * 8;
  int m0 = (t >> 4) * 8, n0 = (t & 15) * 8;
  const float* aptr = abase + (long)lr * a_stride + kq;
  const float* bptr = W + (long)(col0 + lr) * D_ + kq;
  float acc[8][8];
#pragma unroll
  for (int i = 0; i < 8; ++i)
#pragma unroll
    for (int j = 0; j < 8; ++j) acc[i][j] = 0.f;
  for (int kt = 0; kt < D_ / 16; ++kt) {
    float4 av0 = *(const float4*)(aptr);
    float4 av1 = *(const float4*)(aptr + 4);
    float4 bv0 = *(const float4*)(bptr);
    float4 bv1 = *(const float4*)(bptr + 4);
    aptr += 16; bptr += 16;
    __syncthreads();
    As[kq + 0][lr] = av0.x; As[kq + 1][lr] = av0.y;
    As[kq + 2][lr] = av0.z; As[kq + 3][lr] = av0.w;
    As[kq + 4][lr] = av1.x; As[kq + 5][lr] = av1.y;
    As[kq + 6][lr] = av1.z; As[kq + 7][lr] = av1.w;
    Bs[kq + 0][lr] = bv0.x; Bs[kq + 1][lr] = bv0.y;
    Bs[kq + 2][lr] = bv0.z; Bs[kq + 3][lr] = bv0.w;
    Bs[kq + 4][lr] = bv1.x; Bs[kq + 5][lr] = bv1.y;
    Bs[kq + 6][lr] = bv1.z; Bs[kq + 7][lr] = bv1.w;
    __syncthreads();
#pragma unroll
    for (int k = 0; k < 16; ++k) {
      float4 a0 = *(const float4*)&As[k][m0];
      float4 a1 = *(const float4*)&As[k][m0 + 4];
      float4 b0 = *(const float4*)&Bs[k][n0];
      float4 b1 = *(const float4*)&Bs[k][n0 + 4];
      float aa[8] = {a0.x, a0.y, a0.z, a0.w, a1.x, a1.y, a1.z, a1.w};
      float bb[8] = {b0.x, b0.y, b0.z, b0.w, b1.x, b1.y, b1.z, b1.w};
#pragma unroll
      for (int i = 0; i < 8; ++i)
#pragma unroll
        for (int j = 0; j < 8; ++j) acc[i][j] += aa[i] * bb[j];
    }
  }
  float bb[8];
#pragma unroll
  for (int j = 0; j < 8; ++j) bb[j] = bi[col0 + n0 + j];
#pragma unroll
  for (int i = 0; i < 8; ++i) {
    float* cp = cbase + (long)(m0 + i) * c_stride + col0 + n0;
    float4 c0 = {acc[i][0] + bb[0], acc[i][1] + bb[1], acc[i][2] + bb[2], acc[i][3] + bb[3]};
    float4 c1 = {acc[i][4] + bb[4], acc[i][5] + bb[5], acc[i][6] + bb[6], acc[i][7] + bb[7]};
    *(float4*)(cp) = c0;
    *(float4*)(cp + 4) = c1;
  }
}

__global__ __launch_bounds__(256, 2) void attn_f32_kernel(
    float* __restrict__ Q, const float* __restrict__ K, const float* __restrict__ V) {
  int n = blockIdx.x >> 4, h = blockIdx.x & 15;
  int t = threadIdx.x;
  __shared__ float Kc[64][68];
  __shared__ float Vc[64][68];
  float4 qv[16];
  const float* qrow = Q + ((long)(n * BS) + t) * D_ + h * HD;
#pragma unroll
  for (int e = 0; e < 16; ++e) qv[e] = *(const float4*)(qrow + e * 4);
  float m = -3e38f, l = 0.f;
  float4 o4[16];
#pragma unroll
  for (int e = 0; e < 16; ++e) o4[e] = {0.f, 0.f, 0.f, 0.f};
  int sj = t >> 2, se = (t & 3) * 16;
  for (int c = 0; c < 4; ++c) {
    __syncthreads();
    const float* kp = K + ((long)(n * BS + c * 64 + sj)) * D_ + h * HD + se;
    const float* vp = V + ((long)(n * BS + c * 64 + sj)) * D_ + h * HD + se;
#pragma unroll
    for (int i = 0; i < 4; ++i) {
      *(float4*)&Kc[sj][se + i * 4] = *(const float4*)(kp + i * 4);
      *(float4*)&Vc[sj][se + i * 4] = *(const float4*)(vp + i * 4);
    }
    __syncthreads();
    for (int j = 0; j < 64; ++j) {
      float s = 0.f;
#pragma unroll
      for (int e = 0; e < 16; ++e) {
        float4 kv = *(const float4*)&Kc[j][e * 4];
        s += qv[e].x * kv.x + qv[e].y * kv.y + qv[e].z * kv.z + qv[e].w * kv.w;
      }
      s *= 0.125f;
      if (s > m) {
        float sc = __expf(m - s);
        l *= sc;
#pragma unroll
        for (int e = 0; e < 16; ++e) {
          o4[e].x *= sc; o4[e].y *= sc; o4[e].z *= sc; o4[e].w *= sc;
        }
        m = s;
      }
      float p = __expf(s - m);
      l += p;
#pragma unroll
      for (int e = 0; e < 16; ++e) {
        float4 vv = *(const float4*)&Vc[j][e * 4];
        o4[e].x += p * vv.x; o4[e].y += p * vv.y;
        o4[e].z += p * vv.z; o4[e].w += p * vv.w;
      }
    }
  }
  float inv = 1.f / l;
  float* orow = Q + ((long)(n * BS) + t) * D_ + h * HD;
#pragma unroll
  for (int e = 0; e < 16; ++e) {
    float4 ov = {o4[e].x * inv, o4[e].y * inv, o4[e].z * inv, o4[e].w * inv};
    *(float4*)(orow + e * 4) = ov;
  }
}

// ---------------- launch ----------------
extern "C" void kernel_launch(void* const* d_in, const int* in_sizes, int n_in,
                              void* d_out, int out_size, void* d_ws, size_t ws_size,
                              hipStream_t stream) {
  (void)in_sizes; (void)n_in; (void)out_size;
  const float* x  = (const float*)d_in[0];
  const float* Wq = (const float*)d_in[1];
  const float* bq = (const float*)d_in[2];
  const float* Wk = (const float*)d_in[3];
  const float* bk = (const float*)d_in[4];
  const float* Wv = (const float*)d_in[5];
  const float* bv = (const float*)d_in[6];
  const float* Wo = (const float*)d_in[7];
  const float* bo = (const float*)d_in[8];
  float* out = (float*)d_out;
  char* ws = (char*)d_ws;

  // small scratch (1 MB region)
  float* xbf  = (float*)(ws);                   // 64x1024
  float* qbf  = (float*)(ws + 262144);
  float* kbf  = (float*)(ws + 524288);
  float* lgf  = (float*)(ws + 786432);
  int*   perm = (int*)(ws + 790528);

  const size_t NW  = (size_t)D_ * D_;           // 1,048,576
  const size_t NG  = (size_t)2 * S_ * D_;       // 8,388,608 elems per 2-batch group
  const size_t NX  = (size_t)S_ * B_ * D_;      // 16,777,216 elems of x
  const size_t SM  = 1 << 20;

  // fast-path layout: total = 152,043,520 B (same proven footprint)
  size_t off = SM;
  u16* whi  = (u16*)(ws + off); off += 3 * NW * 2;
  u16* wlo  = (u16*)(ws + off); off += 3 * NW * 2;
  u16* wohi = (u16*)(ws + off); off += NW * 2;
  u16* wolo = (u16*)(ws + off); off += NW * 2;
  u16* xhi  = (u16*)(ws + off); off += NX * 2;
  u16* xlo  = (u16*)(ws + off); off += NX * 2;
  u16* Qbf  = (u16*)(ws + off); off += NG * 2;
  u16* Khi  = (u16*)(ws + off); off += NG * 2;
  u16* Klo  = (u16*)(ws + off); off += NG * 2;
  u16* Vbf  = (u16*)(ws + off); off += NG * 2;
  const size_t need = off;

  // aliases: attn output reuses Q/V bf16 buffers (dead at that point per-group)
  u16* aohi = Vbf;
  u16* aolo = Qbf;

  // routing partials live in dead Qbf space on the fast path
  float* xbp = (float*)Qbf;   // 512 x 1024 f32 = 2 MB
  if (ws_size >= need) {
    // merged mean + x hi/lo split: one pass over x (same sum order -> same perm)
    mean1split_kernel<<<512, 256, 0, stream>>>(x, xbp, xhi, xlo);
    mean2_kernel<<<64, 256, 0, stream>>>(xbp, xbf);
  } else {
    mean1_kernel<<<512, 256, 0, stream>>>(x, (float*)(ws + SM));
    mean2_kernel<<<64, 256, 0, stream>>>((float*)(ws + SM), xbf);
  }
  qkblk2_kernel<<<64, 256, 0, stream>>>(xbf, Wq, bq, Wk, bk, qbf, kbf);
  logits_kernel<<<256, 256, 0, stream>>>(qbf, kbf, lgf);
  sinkhorn_kernel<<<4, 256, 0, stream>>>(lgf, perm);

  if (ws_size >= need) {
    wsplit_kernel<<<dim3(1024, 4), 256, 0, stream>>>(Wq, Wk, Wv, Wo, whi, wlo, wohi, wolo);
    for (int grp = 0; grp < 2; ++grp) {
      gemm_qkv_kernel<<<1536, 256, 0, stream>>>(
          xhi, xlo, whi, wlo, bq, bk, bv, Qbf, Khi, Klo, Vbf, perm, grp);
      attn_mfma_kernel<<<512, 256, 0, stream>>>(Qbf, Khi, Klo, Vbf, aohi, aolo);
      gemm_out_kernel<<<512, 256, 0, stream>>>(
          aohi, aolo, wohi, wolo, bo, out, grp);
    }
  } else {
    // Tier C: proven fp32 path (49 MB)
    float* Qb = (float*)(ws + 4 * SM);
    float* Kb = Qb + (size_t)S_ * D_;
    float* Vb = Kb + (size_t)S_ * D_;
    for (int b = 0; b < B_; ++b) {
      gemm_f32_kernel<<<dim3(8, 32, 3), 256, 0, stream>>>(
          x, Wq, Wk, Wv, bq, bk, bv, Qb, Kb, Vb, perm, b, 0);
      attn_f32_kernel<<<256, 256, 0, stream>>>(Qb, Kb, Vb);
      gemm_f32_kernel<<<dim3(8, 32, 1), 256, 0, stream>>>(
          Qb, Wo, Wo, Wo, bo, bo, bo, out, out, out, perm, b, 1);
    }
  }
}

// Round 9
// 441.903 us; speedup vs baseline: 1.8913x; 1.5498x over previous
//
#include <hip/hip_runtime.h>
#include <math.h>

typedef unsigned short u16;
typedef _Float16 f16t;
typedef f16t f16x8 __attribute__((ext_vector_type(8)));
typedef u16 u16x8 __attribute__((ext_vector_type(8)));
typedef float f32x4 __attribute__((ext_vector_type(4)));

#define D_ 1024
#define S_ 4096
#define B_ 4
#define NB 16
#define BS 256
#define NH 16
#define HD 64

__device__ __forceinline__ u16 f2hu(float f) {
  f16t h = (f16t)f;              // v_cvt_f16_f32, RNE
  u16 u; __builtin_memcpy(&u, &h, 2); return u;
}
__device__ __forceinline__ f16x8 u2h8(u16x8 u) {
  f16x8 r; __builtin_memcpy(&r, &u, 16); return r;
}
__device__ __forceinline__ void gld_lds16(const void* g, void* l) {
  __builtin_amdgcn_global_load_lds((__attribute__((address_space(1))) void*)g,
                                   (__attribute__((address_space(3))) void*)l, 16, 0, 0);
}

// ---------------- block means, two-stage ----------------
// Tier C variant
__global__ __launch_bounds__(256) void mean1_kernel(const float* __restrict__ x,
                                                    float* __restrict__ xbp) {
  int bx = blockIdx.x;
  int o = bx >> 3, p = bx & 7;
  int b = o >> 4, n = o & 15;
  int t = threadIdx.x;
  float4 acc = {0.f, 0.f, 0.f, 0.f};
  const float* xp = x + ((long)(n * BS + p * 32) * B_ + b) * D_ + t * 4;
  for (int s = 0; s < 32; ++s) {
    float4 u = *(const float4*)xp;
    acc.x += u.x; acc.y += u.y; acc.z += u.z; acc.w += u.w;
    xp += B_ * D_;
  }
  *(float4*)(xbp + (long)bx * D_ + t * 4) = acc;
}
// fast path: same reads & bit-identical sum order + fp16 store of x (one plane)
__global__ __launch_bounds__(256) void mean1h_kernel(const float* __restrict__ x,
    float* __restrict__ xbp, u16* __restrict__ xh) {
  int bx = blockIdx.x;
  int o = bx >> 3, p = bx & 7;
  int b = o >> 4, n = o & 15;
  int t = threadIdx.x;
  float4 acc = {0.f, 0.f, 0.f, 0.f};
  long base = ((long)(n * BS + p * 32) * B_ + b) * D_ + t * 4;
  const float* xp = x + base;
  long idx = base;
  for (int s = 0; s < 32; ++s) {
    float4 u = *(const float4*)xp;
    acc.x += u.x; acc.y += u.y; acc.z += u.z; acc.w += u.w;
    ushort4 h;
    h.x = f2hu(u.x); h.y = f2hu(u.y); h.z = f2hu(u.z); h.w = f2hu(u.w);
    *(ushort4*)(xh + idx) = h;
    xp += B_ * D_;
    idx += B_ * D_;
  }
  *(float4*)(xbp + (long)bx * D_ + t * 4) = acc;
}
__global__ __launch_bounds__(256) void mean2_kernel(const float* __restrict__ xbp,
                                                    float* __restrict__ xb) {
  int o = blockIdx.x, t = threadIdx.x;
  float4 acc = {0.f, 0.f, 0.f, 0.f};
#pragma unroll
  for (int p = 0; p < 8; ++p) {
    float4 u = *(const float4*)(xbp + (long)(o * 8 + p) * D_ + t * 4);
    acc.x += u.x; acc.y += u.y; acc.z += u.z; acc.w += u.w;
  }
  float4 r = {acc.x * (1.f / BS), acc.y * (1.f / BS), acc.z * (1.f / BS), acc.w * (1.f / BS)};
  *(float4*)(xb + (long)o * D_ + t * 4) = r;
}

// ---------------- q_blk / k_blk ----------------
__global__ __launch_bounds__(256) void qkblk2_kernel(const float* __restrict__ xb,
    const float* __restrict__ Wq, const float* __restrict__ bq,
    const float* __restrict__ Wk, const float* __restrict__ bk,
    float* __restrict__ qb, float* __restrict__ kb) {
  int m = blockIdx.x >> 5, ct = blockIdx.x & 31;
  const float* W  = m ? Wk : Wq;
  const float* bi = m ? bk : bq;
  float* out      = m ? kb : qb;
  __shared__ float As[64][132];
  __shared__ float Ws[32][132];
  int t = threadIdx.x;
  int col = t & 31, rg = t >> 5;
  float acc[8];
#pragma unroll
  for (int i = 0; i < 8; ++i) acc[i] = 0.f;
  int srow = t >> 2, sks = (t & 3) * 32;
  for (int kc = 0; kc < 8; ++kc) {
    int k0 = kc * 128;
    __syncthreads();
#pragma unroll
    for (int j = 0; j < 8; ++j)
      *(float4*)&As[srow][sks + j * 4] = *(const float4*)(xb + (long)srow * D_ + k0 + sks + j * 4);
    if (t < 128) {
      int c = t >> 2, ks = (t & 3) * 32;
#pragma unroll
      for (int j = 0; j < 8; ++j)
        *(float4*)&Ws[c][ks + j * 4] =
            *(const float4*)(W + (long)(ct * 32 + c) * D_ + k0 + ks + j * 4);
    }
    __syncthreads();
#pragma unroll
    for (int k4 = 0; k4 < 32; ++k4) {
      float4 wv = *(const float4*)&Ws[col][k4 * 4];
#pragma unroll
      for (int i = 0; i < 8; ++i) {
        float4 av = *(const float4*)&As[rg * 8 + i][k4 * 4];
        acc[i] += av.x * wv.x + av.y * wv.y + av.z * wv.z + av.w * wv.w;
      }
    }
  }
  float bv = bi[ct * 32 + col];
#pragma unroll
  for (int i = 0; i < 8; ++i)
    out[(long)(rg * 8 + i) * D_ + ct * 32 + col] = acc[i] + bv;
}

// ---------------- logits ----------------
__global__ __launch_bounds__(256) void logits_kernel(const float* __restrict__ qb,
                                                     const float* __restrict__ kb,
                                                     float* __restrict__ lg) {
  int idx = blockIdx.x * 4 + (threadIdx.x >> 6);
  int b = idx >> 8, n = (idx >> 4) & 15, m = idx & 15;
  int lane = threadIdx.x & 63;
  float acc = 0.f;
  const float* qp = qb + (b * 16 + n) * D_ + lane;
  const float* kp = kb + (b * 16 + m) * D_ + lane;
#pragma unroll
  for (int kk = 0; kk < 16; ++kk) acc += qp[kk * 64] * kp[kk * 64];
#pragma unroll
  for (int mm = 1; mm < 64; mm <<= 1) acc += __shfl_xor(acc, mm);
  if (lane == 0) lg[idx] = acc * (1.f / 32.f);
}

// ---------------- Sinkhorn + argmax ----------------
__global__ __launch_bounds__(256) void sinkhorn_kernel(const float* __restrict__ lg,
                                                       int* __restrict__ perm) {
  int b = blockIdx.x;
  __shared__ float L[16][17];
  int t = threadIdx.x;
  int n = t >> 4, m = t & 15;
  L[n][m] = lg[b * 256 + t];
  __syncthreads();
  for (int it = 0; it < 5; ++it) {
    float mx = -3e38f;
#pragma unroll
    for (int i = 0; i < 16; ++i) mx = fmaxf(mx, L[n][i]);
    float sm = 0.f;
#pragma unroll
    for (int i = 0; i < 16; ++i) sm += expf(L[n][i] - mx);
    float lse = mx + logf(sm);
    __syncthreads();
    L[n][m] -= lse;
    __syncthreads();
    mx = -3e38f;
#pragma unroll
    for (int i = 0; i < 16; ++i) mx = fmaxf(mx, L[i][m]);
    sm = 0.f;
#pragma unroll
    for (int i = 0; i < 16; ++i) sm += expf(L[i][m] - mx);
    lse = mx + logf(sm);
    __syncthreads();
    L[n][m] -= lse;
    __syncthreads();
  }
  if (t < 16) {
    float best = -3e38f; int bi = 0;
#pragma unroll
    for (int i = 0; i < 16; ++i) {
      float v = L[t][i];
      if (v > best) { best = v; bi = i; }
    }
    perm[b * 16 + t] = bi;
  }
}

// ---------------- weight convert: 4 matrices -> fp16 (one plane each) -----------
__global__ __launch_bounds__(256) void whalf_kernel(
    const float* __restrict__ Wq, const float* __restrict__ Wk,
    const float* __restrict__ Wv, const float* __restrict__ Wo,
    u16* __restrict__ wh, u16* __restrict__ woh) {
  const size_t NW = (size_t)D_ * D_;
  int z = blockIdx.y;
  const float* src = (z == 0) ? Wq : (z == 1) ? Wk : (z == 2) ? Wv : Wo;
  u16* dh = (z < 3) ? (wh + (size_t)z * NW) : woh;
  long i = (long)blockIdx.x * 256 + threadIdx.x;
  float4 v = ((const float4*)src)[i];
  ushort4 h;
  h.x = f2hu(v.x); h.y = f2hu(v.y); h.z = f2hu(v.z); h.w = f2hu(v.w);
  ((ushort4*)dh)[i] = h;
}

// ---------------- QKV GEMM v8: fp16 1-term, counted-vmcnt 2-deep, 32KB LDS -------
// Single fp16 plane per operand: 1 MFMA term (was 3), 4 gld_lds per stage (was 8).
// 2 buffers = 32 KB total -> 4 blocks/CU (fixes r8's occupancy tax). Main loop
// waits vmcnt(4): the just-issued tile's loads stay in flight under the MFMA.
__global__ __launch_bounds__(256, 4) void gemm_qkv_kernel(
    const u16* __restrict__ xh, const u16* __restrict__ wh,
    const float* __restrict__ bq, const float* __restrict__ bk, const float* __restrict__ bv,
    u16* __restrict__ Qh, u16* __restrict__ Kh, u16* __restrict__ Vh,
    const int* __restrict__ perm, int grp) {
  int hw = blockIdx.x;
  int xcd = hw & 7, idx = hw >> 3;       // idx 0..191
  int yl = idx / 24, rem = idx - yl * 24;
  int z = rem >> 3, xt = rem & 7;
  int y = xcd * 8 + yl;                  // 0..63
  const u16* Wp = wh + (size_t)z * (D_ * D_);
  const float* bi = (z == 0) ? bq : (z == 1) ? bk : bv;
  int g = y >> 5, st = y & 31;
  int b = grp * 2 + g;
  int col0 = xt * 128;
  int n = st >> 1;
  int sb = perm[b * NB + n];
  const long a_stride = (long)B_ * D_;
  long a_off = ((long)(sb * BS + (st & 1) * 128) * B_ + b) * D_;
  const u16* Ahg = xh + a_off;

  __shared__ __attribute__((aligned(16))) u16 Ash[2][4096], Bsh[2][4096];
  int t = threadIdx.x;
  int w = t >> 6, lane = t & 63, quad = lane >> 4, l15 = lane & 15;
  int wm = w >> 1, wn = w & 1;
  f32x4 acc[4][4];
#pragma unroll
  for (int i = 0; i < 4; ++i)
#pragma unroll
    for (int j = 0; j < 4; ++j) acc[i][j] = {0.f, 0.f, 0.f, 0.f};

  int ch0 = t, ch1 = t + 256;
  int r0 = ch0 >> 2, kc0 = ((ch0 & 3) ^ ((ch0 >> 3) & 3)) * 8;
  int r1 = ch1 >> 2, kc1 = ((ch1 & 3) ^ ((ch1 >> 3) & 3)) * 8;
  int cswz = (quad ^ ((l15 >> 1) & 3)) * 8;

#define QKV_STAGE(BUF, K0)                                                     \
  do {                                                                         \
    gld_lds16(Ahg + (long)r0 * a_stride + (K0) + kc0, &Ash[BUF][ch0 * 8]);     \
    gld_lds16(Ahg + (long)r1 * a_stride + (K0) + kc1, &Ash[BUF][ch1 * 8]);     \
    gld_lds16(Wp + (long)(col0 + r0) * D_ + (K0) + kc0, &Bsh[BUF][ch0 * 8]);   \
    gld_lds16(Wp + (long)(col0 + r1) * D_ + (K0) + kc1, &Bsh[BUF][ch1 * 8]);   \
  } while (0)

#define QKV_READ(BUF)                                                          \
  do {                                                                         \
    _Pragma("unroll") for (int i = 0; i < 4; ++i)                              \
      ah[i] = *(const f16x8*)(&Ash[BUF][0] + (wm * 64 + i * 16 + l15) * 32 + cswz); \
    _Pragma("unroll") for (int j = 0; j < 4; ++j)                              \
      bh[j] = *(const f16x8*)(&Bsh[BUF][0] + (wn * 64 + j * 16 + l15) * 32 + cswz); \
  } while (0)

#define QKV_MFMA                                                               \
  do {                                                                         \
    _Pragma("unroll") for (int i = 0; i < 4; ++i)                              \
      _Pragma("unroll") for (int j = 0; j < 4; ++j)                            \
        acc[i][j] = __builtin_amdgcn_mfma_f32_16x16x32_f16(ah[i], bh[j], acc[i][j], 0, 0, 0); \
  } while (0)

  QKV_STAGE(0, 0);
  QKV_STAGE(1, 32);
#pragma unroll 1
  for (int kt = 0; kt < 31; ++kt) {
    f16x8 ah[4], bh[4];
    asm volatile("s_waitcnt vmcnt(4)" ::: "memory");   // tile kt landed; kt+1 in flight
    __builtin_amdgcn_s_barrier();
    QKV_READ(kt & 1);
    asm volatile("s_waitcnt lgkmcnt(0)" ::: "memory");
    __builtin_amdgcn_s_barrier();
    if (kt < 30) QKV_STAGE(kt & 1, (kt + 2) * 32);
    QKV_MFMA;
  }
  {
    f16x8 ah[4], bh[4];
    asm volatile("s_waitcnt vmcnt(0)" ::: "memory");
    __builtin_amdgcn_s_barrier();
    QKV_READ(1);
    QKV_MFMA;
  }
#undef QKV_STAGE
#undef QKV_READ
#undef QKV_MFMA

#pragma unroll
  for (int j = 0; j < 4; ++j) {
    float bvv = bi[col0 + wn * 64 + j * 16 + l15];
#pragma unroll
    for (int i = 0; i < 4; ++i) {
      int row = wm * 64 + i * 16 + quad * 4;
      long base = ((long)g * S_ + st * 128 + row) * D_ + col0 + wn * 64 + j * 16 + l15;
#pragma unroll
      for (int r = 0; r < 4; ++r) {
        float val = acc[i][j][r] + bvv;
        long a = base + (long)r * D_;
        if (z == 0) {
          Qh[a] = f2hu(val * 0.125f);
        } else if (z == 1) {
          Kh[a] = f2hu(val);
        } else {
          Vh[a] = f2hu(val);
        }
      }
    }
  }
}

// ---------------- out GEMM: fp16 1-term, counted-vmcnt, XCD-aware ----------------
__global__ __launch_bounds__(256, 4) void gemm_out_kernel(
    const u16* __restrict__ aoh, const u16* __restrict__ woh,
    const float* __restrict__ bo, float* __restrict__ out, int grp) {
  int hw = blockIdx.x;
  int xcd = hw & 7, idx = hw >> 3;       // idx 0..63
  int yl = idx >> 3, xt = idx & 7;
  int y = xcd * 8 + yl;                  // 0..63
  int g = y >> 5, st = y & 31;
  int b = grp * 2 + g;
  int col0 = xt * 128;
  long a_off = ((long)g * S_ + st * 128) * D_;
  const u16* Ah = aoh + a_off;
  float* cbase = out + ((long)(st * 128) * B_ + b) * D_;
  const long c_stride = (long)B_ * D_;

  __shared__ __attribute__((aligned(16))) u16 Ash[2][4096], Bsh[2][4096];
  int t = threadIdx.x;
  int w = t >> 6, lane = t & 63, quad = lane >> 4, l15 = lane & 15;
  int wm = w >> 1, wn = w & 1;
  f32x4 acc[4][4];
#pragma unroll
  for (int i = 0; i < 4; ++i)
#pragma unroll
    for (int j = 0; j < 4; ++j) acc[i][j] = {0.f, 0.f, 0.f, 0.f};

  int ch0 = t, ch1 = t + 256;
  int r0 = ch0 >> 2, kc0 = ((ch0 & 3) ^ ((ch0 >> 3) & 3)) * 8;
  int r1 = ch1 >> 2, kc1 = ((ch1 & 3) ^ ((ch1 >> 3) & 3)) * 8;
  int cswz = (quad ^ ((l15 >> 1) & 3)) * 8;

#define OUT_STAGE(BUF, K0)                                                      \
  do {                                                                          \
    gld_lds16(Ah + (long)r0 * D_ + (K0) + kc0, &Ash[BUF][ch0 * 8]);             \
    gld_lds16(Ah + (long)r1 * D_ + (K0) + kc1, &Ash[BUF][ch1 * 8]);             \
    gld_lds16(woh + (long)(col0 + r0) * D_ + (K0) + kc0, &Bsh[BUF][ch0 * 8]);   \
    gld_lds16(woh + (long)(col0 + r1) * D_ + (K0) + kc1, &Bsh[BUF][ch1 * 8]);   \
  } while (0)

#define OUT_READ(BUF)                                                           \
  do {                                                                          \
    _Pragma("unroll") for (int i = 0; i < 4; ++i)                               \
      ah[i] = *(const f16x8*)(&Ash[BUF][0] + (wm * 64 + i * 16 + l15) * 32 + cswz); \
    _Pragma("unroll") for (int j = 0; j < 4; ++j)                               \
      bh[j] = *(const f16x8*)(&Bsh[BUF][0] + (wn * 64 + j * 16 + l15) * 32 + cswz); \
  } while (0)

#define OUT_MFMA                                                                \
  do {                                                                          \
    _Pragma("unroll") for (int i = 0; i < 4; ++i)                               \
      _Pragma("unroll") for (int j = 0; j < 4; ++j)                             \
        acc[i][j] = __builtin_amdgcn_mfma_f32_16x16x32_f16(ah[i], bh[j], acc[i][j], 0, 0, 0); \
  } while (0)

  OUT_STAGE(0, 0);
  OUT_STAGE(1, 32);
#pragma unroll 1
  for (int kt = 0; kt < 31; ++kt) {
    f16x8 ah[4], bh[4];
    asm volatile("s_waitcnt vmcnt(4)" ::: "memory");
    __builtin_amdgcn_s_barrier();
    OUT_READ(kt & 1);
    asm volatile("s_waitcnt lgkmcnt(0)" ::: "memory");
    __builtin_amdgcn_s_barrier();
    if (kt < 30) OUT_STAGE(kt & 1, (kt + 2) * 32);
    OUT_MFMA;
  }
  {
    f16x8 ah[4], bh[4];
    asm volatile("s_waitcnt vmcnt(0)" ::: "memory");
    __builtin_amdgcn_s_barrier();
    OUT_READ(1);
    OUT_MFMA;
  }
#undef OUT_STAGE
#undef OUT_READ
#undef OUT_MFMA

#pragma unroll
  for (int j = 0; j < 4; ++j) {
    float bvv = bo[col0 + wn * 64 + j * 16 + l15];
#pragma unroll
    for (int i = 0; i < 4; ++i) {
      int row = wm * 64 + i * 16 + quad * 4;
      long base = (long)row * c_stride + col0 + wn * 64 + j * 16 + l15;
#pragma unroll
      for (int r = 0; r < 4; ++r)
        cbase[base + (long)r * c_stride] = acc[i][j][r] + bvv;
    }
  }
}

// ---------------- block-local attention, MFMA flash, fp16 throughout -------------
// Qh pre-scaled 0.125; K single fp16 plane (1-term QK^T); P stored fp16 (8x less
// rounding than bf16 -> dominant absmax term shrinks); denom via ones-MFMA with the
// same rounded P. aoh aliases Vh (per-block region read-complete before write).
__global__ __launch_bounds__(256, 2) void attn_mfma_kernel(
    const u16* __restrict__ Qh, const u16* __restrict__ KhG,
    const u16* __restrict__ Vh, u16* __restrict__ aoh) {
  int g = blockIdx.x >> 8;
  int n = (blockIdx.x >> 4) & 15, h = blockIdx.x & 15;
  long rbase = (long)g * S_ + n * BS;
  int t = threadIdx.x;
  int w = t >> 6, lane = t & 63, quad = lane >> 4, l15 = lane & 15;

  __shared__ __attribute__((aligned(16))) u16 Kc[64][72];
  __shared__ __attribute__((aligned(16))) u16 Vt[64][72];   // transposed: [d][key]
  __shared__ __attribute__((aligned(16))) u16 Pw[4][64][72];

  f16x8 vones;
  {
    u16x8 uo;
#pragma unroll
    for (int e = 0; e < 8; ++e) uo[e] = 0x3C00u;  // fp16 1.0
    vones = u2h8(uo);
  }

  f16x8 qf[4][2];
#pragma unroll
  for (int i = 0; i < 4; ++i)
#pragma unroll
    for (int ks = 0; ks < 2; ++ks)
      qf[i][ks] = u2h8(*(const u16x8*)(Qh +
          (rbase + w * 64 + i * 16 + l15) * (long)D_ + h * HD + ks * 32 + quad * 8));

  f32x4 acc[4][4];
  f32x4 accl[4];
  float m[4][4];
#pragma unroll
  for (int i = 0; i < 4; ++i) {
    accl[i] = {0.f, 0.f, 0.f, 0.f};
#pragma unroll
    for (int j = 0; j < 4; ++j) {
      acc[i][j] = {0.f, 0.f, 0.f, 0.f};
      m[i][j] = -3e38f;
    }
  }

  int skey = t >> 2, sd0 = (t & 3) * 16;

#pragma unroll 1
  for (int c = 0; c < 4; ++c) {
    __syncthreads();
    {
      long roff = (rbase + c * 64 + skey) * (long)D_ + h * HD + sd0;
      u16x8 k0 = *(const u16x8*)(KhG + roff);
      u16x8 k1 = *(const u16x8*)(KhG + roff + 8);
      *(u16x8*)&Kc[skey][sd0] = k0;
      *(u16x8*)&Kc[skey][sd0 + 8] = k1;
      u16x8 v0 = *(const u16x8*)(Vh + roff);
      u16x8 v1 = *(const u16x8*)(Vh + roff + 8);
#pragma unroll
      for (int e = 0; e < 8; ++e) {
        Vt[sd0 + e][skey] = v0[e];
        Vt[sd0 + 8 + e][skey] = v1[e];
      }
    }
    __syncthreads();

    f32x4 s[4][4];
#pragma unroll
    for (int i = 0; i < 4; ++i)
#pragma unroll
      for (int j = 0; j < 4; ++j) s[i][j] = {0.f, 0.f, 0.f, 0.f};
    __builtin_amdgcn_s_setprio(1);
#pragma unroll
    for (int ks = 0; ks < 2; ++ks)
#pragma unroll
      for (int j = 0; j < 4; ++j) {
        f16x8 kh = *(const f16x8*)&Kc[j * 16 + l15][ks * 32 + quad * 8];
#pragma unroll
        for (int i = 0; i < 4; ++i)
          s[i][j] = __builtin_amdgcn_mfma_f32_16x16x32_f16(qf[i][ks], kh, s[i][j], 0, 0, 0);
      }
    __builtin_amdgcn_s_setprio(0);

#pragma unroll
    for (int i = 0; i < 4; ++i)
#pragma unroll
      for (int r = 0; r < 4; ++r) {
        float mc = fmaxf(fmaxf(s[i][0][r], s[i][1][r]), fmaxf(s[i][2][r], s[i][3][r]));
#pragma unroll
        for (int mk = 1; mk < 16; mk <<= 1) mc = fmaxf(mc, __shfl_xor(mc, mk));
        float mn = fmaxf(m[i][r], mc);
        float sc = __expf(m[i][r] - mn);
        m[i][r] = mn;
#pragma unroll
        for (int j = 0; j < 4; ++j) {
          float p = __expf(s[i][j][r] - mn);
          Pw[w][i * 16 + quad * 4 + r][j * 16 + l15] = f2hu(p);
        }
        accl[i][r] *= sc;
#pragma unroll
        for (int jd = 0; jd < 4; ++jd) acc[i][jd][r] *= sc;
      }
    __syncthreads();

    __builtin_amdgcn_s_setprio(1);
#pragma unroll
    for (int ks = 0; ks < 2; ++ks) {
      f16x8 pa[4], vb[4];
#pragma unroll
      for (int i = 0; i < 4; ++i)
        pa[i] = *(const f16x8*)&Pw[w][i * 16 + l15][ks * 32 + quad * 8];
#pragma unroll
      for (int jd = 0; jd < 4; ++jd)
        vb[jd] = *(const f16x8*)&Vt[jd * 16 + l15][ks * 32 + quad * 8];
#pragma unroll
      for (int i = 0; i < 4; ++i) {
#pragma unroll
        for (int jd = 0; jd < 4; ++jd)
          acc[i][jd] = __builtin_amdgcn_mfma_f32_16x16x32_f16(pa[i], vb[jd], acc[i][jd], 0, 0, 0);
        accl[i] = __builtin_amdgcn_mfma_f32_16x16x32_f16(pa[i], vones, accl[i], 0, 0, 0);
      }
    }
    __builtin_amdgcn_s_setprio(0);
  }

#pragma unroll
  for (int i = 0; i < 4; ++i) {
    float il[4];
#pragma unroll
    for (int r = 0; r < 4; ++r) il[r] = 1.f / accl[i][r];
#pragma unroll
    for (int jd = 0; jd < 4; ++jd)
#pragma unroll
      for (int r = 0; r < 4; ++r) {
        float f = acc[i][jd][r] * il[r];
        long addr = (rbase + w * 64 + i * 16 + quad * 4 + r) * (long)D_ + h * HD + jd * 16 + l15;
        aoh[addr] = f2hu(f);
      }
  }
}

// ================= Tier C fallback (proven fp32 path) =================
__global__ __launch_bounds__(256, 2) void gemm_f32_kernel(
    const float* __restrict__ A0,
    const float* __restrict__ W0, const float* __restrict__ W1, const float* __restrict__ W2,
    const float* __restrict__ bi0, const float* __restrict__ bi1, const float* __restrict__ bi2,
    float* __restrict__ O0, float* __restrict__ O1, float* __restrict__ O2,
    const int* __restrict__ perm, int b, int mode) {
  int z = blockIdx.z;
  const float* W  = (z == 0) ? W0 : (z == 1 ? W1 : W2);
  const float* bi = (z == 0) ? bi0 : (z == 1 ? bi1 : bi2);
  float* C        = (z == 0) ? O0 : (z == 1 ? O1 : O2);
  int st = blockIdx.y;
  int col0 = blockIdx.x * 128;
  const float* abase; float* cbase; long a_stride, c_stride;
  if (mode == 0) {
    int n = st >> 1;
    int sb = perm[b * NB + n];
    long a_row0 = (long)sb * BS + (st & 1) * 128;
    abase = A0 + (a_row0 * B_ + b) * D_;
    a_stride = (long)B_ * D_;
    cbase = C + (long)(st * 128) * D_;
    c_stride = D_;
  } else {
    abase = A0 + (long)(st * 128) * D_;
    a_stride = D_;
    cbase = C + ((long)(st * 128) * B_ + b) * D_;
    c_stride = (long)B_ * D_;
  }
  __shared__ float As[16][132];
  __shared__ float Bs[16][132];
  int t = threadIdx.x;
  int lr = t >> 1, kq = (t & 1) * 8;
  int m0 = (t >> 4) * 8, n0 = (t & 15) * 8;
  const float* aptr = abase + (long)lr * a_stride + kq;
  const float* bptr = W + (long)(col0 + lr) * D_ + kq;
  float acc[8][8];
#pragma unroll
  for (int i = 0; i < 8; ++i)
#pragma unroll
    for (int j = 0; j < 8; ++j) acc[i][j] = 0.f;
  for (int kt = 0; kt < D_ / 16; ++kt) {
    float4 av0 = *(const float4*)(aptr);
    float4 av1 = *(const float4*)(aptr + 4);
    float4 bv0 = *(const float4*)(bptr);
    float4 bv1 = *(const float4*)(bptr + 4);
    aptr += 16; bptr += 16;
    __syncthreads();
    As[kq + 0][lr] = av0.x; As[kq + 1][lr] = av0.y;
    As[kq + 2][lr] = av0.z; As[kq + 3][lr] = av0.w;
    As[kq + 4][lr] = av1.x; As[kq + 5][lr] = av1.y;
    As[kq + 6][lr] = av1.z; As[kq + 7][lr] = av1.w;
    Bs[kq + 0][lr] = bv0.x; Bs[kq + 1][lr] = bv0.y;
    Bs[kq + 2][lr] = bv0.z; Bs[kq + 3][lr] = bv0.w;
    Bs[kq + 4][lr] = bv1.x; Bs[kq + 5][lr] = bv1.y;
    Bs[kq + 6][lr] = bv1.z; Bs[kq + 7][lr] = bv1.w;
    __syncthreads();
#pragma unroll
    for (int k = 0; k < 16; ++k) {
      float4 a0 = *(const float4*)&As[k][m0];
      float4 a1 = *(const float4*)&As[k][m0 + 4];
      float4 b0 = *(const float4*)&Bs[k][n0];
      float4 b1 = *(const float4*)&Bs[k][n0 + 4];
      float aa[8] = {a0.x, a0.y, a0.z, a0.w, a1.x, a1.y, a1.z, a1.w};
      float bb[8] = {b0.x, b0.y, b0.z, b0.w, b1.x, b1.y, b1.z, b1.w};
#pragma unroll
      for (int i = 0; i < 8; ++i)
#pragma unroll
        for (int j = 0; j < 8; ++j) acc[i][j] += aa[i] * bb[j];
    }
  }
  float bb[8];
#pragma unroll
  for (int j = 0; j < 8; ++j) bb[j] = bi[col0 + n0 + j];
#pragma unroll
  for (int i = 0; i < 8; ++i) {
    float* cp = cbase + (long)(m0 + i) * c_stride + col0 + n0;
    float4 c0 = {acc[i][0] + bb[0], acc[i][1] + bb[1], acc[i][2] + bb[2], acc[i][3] + bb[3]};
    float4 c1 = {acc[i][4] + bb[4], acc[i][5] + bb[5], acc[i][6] + bb[6], acc[i][7] + bb[7]};
    *(float4*)(cp) = c0;
    *(float4*)(cp + 4) = c1;
  }
}

__global__ __launch_bounds__(256, 2) void attn_f32_kernel(
    float* __restrict__ Q, const float* __restrict__ K, const float* __restrict__ V) {
  int n = blockIdx.x >> 4, h = blockIdx.x & 15;
  int t = threadIdx.x;
  __shared__ float Kc[64][68];
  __shared__ float Vc[64][68];
  float4 qv[16];
  const float* qrow = Q + ((long)(n * BS) + t) * D_ + h * HD;
#pragma unroll
  for (int e = 0; e < 16; ++e) qv[e] = *(const float4*)(qrow + e * 4);
  float m = -3e38f, l = 0.f;
  float4 o4[16];
#pragma unroll
  for (int e = 0; e < 16; ++e) o4[e] = {0.f, 0.f, 0.f, 0.f};
  int sj = t >> 2, se = (t & 3) * 16;
  for (int c = 0; c < 4; ++c) {
    __syncthreads();
    const float* kp = K + ((long)(n * BS + c * 64 + sj)) * D_ + h * HD + se;
    const float* vp = V + ((long)(n * BS + c * 64 + sj)) * D_ + h * HD + se;
#pragma unroll
    for (int i = 0; i < 4; ++i) {
      *(float4*)&Kc[sj][se + i * 4] = *(const float4*)(kp + i * 4);
      *(float4*)&Vc[sj][se + i * 4] = *(const float4*)(vp + i * 4);
    }
    __syncthreads();
    for (int j = 0; j < 64; ++j) {
      float s = 0.f;
#pragma unroll
      for (int e = 0; e < 16; ++e) {
        float4 kv = *(const float4*)&Kc[j][e * 4];
        s += qv[e].x * kv.x + qv[e].y * kv.y + qv[e].z * kv.z + qv[e].w * kv.w;
      }
      s *= 0.125f;
      if (s > m) {
        float sc = __expf(m - s);
        l *= sc;
#pragma unroll
        for (int e = 0; e < 16; ++e) {
          o4[e].x *= sc; o4[e].y *= sc; o4[e].z *= sc; o4[e].w *= sc;
        }
        m = s;
      }
      float p = __expf(s - m);
      l += p;
#pragma unroll
      for (int e = 0; e < 16; ++e) {
        float4 vv = *(const float4*)&Vc[j][e * 4];
        o4[e].x += p * vv.x; o4[e].y += p * vv.y;
        o4[e].z += p * vv.z; o4[e].w += p * vv.w;
      }
    }
  }
  float inv = 1.f / l;
  float* orow = Q + ((long)(n * BS) + t) * D_ + h * HD;
#pragma unroll
  for (int e = 0; e < 16; ++e) {
    float4 ov = {o4[e].x * inv, o4[e].y * inv, o4[e].z * inv, o4[e].w * inv};
    *(float4*)(orow + e * 4) = ov;
  }
}

// ---------------- launch ----------------
extern "C" void kernel_launch(void* const* d_in, const int* in_sizes, int n_in,
                              void* d_out, int out_size, void* d_ws, size_t ws_size,
                              hipStream_t stream) {
  (void)in_sizes; (void)n_in; (void)out_size;
  const float* x  = (const float*)d_in[0];
  const float* Wq = (const float*)d_in[1];
  const float* bq = (const float*)d_in[2];
  const float* Wk = (const float*)d_in[3];
  const float* bk = (const float*)d_in[4];
  const float* Wv = (const float*)d_in[5];
  const float* bv = (const float*)d_in[6];
  const float* Wo = (const float*)d_in[7];
  const float* bo = (const float*)d_in[8];
  float* out = (float*)d_out;
  char* ws = (char*)d_ws;

  // small scratch (1 MB region)
  float* xbf  = (float*)(ws);                   // 64x1024
  float* qbf  = (float*)(ws + 262144);
  float* kbf  = (float*)(ws + 524288);
  float* lgf  = (float*)(ws + 786432);
  int*   perm = (int*)(ws + 790528);

  const size_t NW  = (size_t)D_ * D_;           // 1,048,576
  const size_t NG  = (size_t)2 * S_ * D_;       // 8,388,608 elems per 2-batch group
  const size_t NX  = (size_t)S_ * B_ * D_;      // 16,777,216 elems of x
  const size_t SM  = 1 << 20;

  // fast-path layout (fp16 single planes): ~93 MB, well under the proven 152 MB
  size_t off = SM;
  u16* wh   = (u16*)(ws + off); off += 3 * NW * 2;
  u16* woh  = (u16*)(ws + off); off += NW * 2;
  u16* xh   = (u16*)(ws + off); off += NX * 2;
  u16* Qh   = (u16*)(ws + off); off += NG * 2;
  u16* Kh   = (u16*)(ws + off); off += NG * 2;
  u16* Vh   = (u16*)(ws + off); off += NG * 2;
  const size_t need = off;

  // attn output aliases Vh (per-block regions read-complete before epilogue write)
  u16* aoh = Vh;

  // routing partials live in dead Qh space on the fast path
  float* xbp = (float*)Qh;   // 512 x 1024 f32 = 2 MB
  if (ws_size >= need) {
    mean1h_kernel<<<512, 256, 0, stream>>>(x, xbp, xh);
    mean2_kernel<<<64, 256, 0, stream>>>(xbp, xbf);
  } else {
    mean1_kernel<<<512, 256, 0, stream>>>(x, (float*)(ws + SM));
    mean2_kernel<<<64, 256, 0, stream>>>((float*)(ws + SM), xbf);
  }
  qkblk2_kernel<<<64, 256, 0, stream>>>(xbf, Wq, bq, Wk, bk, qbf, kbf);
  logits_kernel<<<256, 256, 0, stream>>>(qbf, kbf, lgf);
  sinkhorn_kernel<<<4, 256, 0, stream>>>(lgf, perm);

  if (ws_size >= need) {
    whalf_kernel<<<dim3(1024, 4), 256, 0, stream>>>(Wq, Wk, Wv, Wo, wh, woh);
    for (int grp = 0; grp < 2; ++grp) {
      gemm_qkv_kernel<<<1536, 256, 0, stream>>>(
          xh, wh, bq, bk, bv, Qh, Kh, Vh, perm, grp);
      attn_mfma_kernel<<<512, 256, 0, stream>>>(Qh, Kh, Vh, aoh);
      gemm_out_kernel<<<512, 256, 0, stream>>>(
          aoh, woh, bo, out, grp);
    }
  } else {
    // Tier C: proven fp32 path (49 MB)
    float* Qb = (float*)(ws + 4 * SM);
    float* Kb = Qb + (size_t)S_ * D_;
    float* Vb = Kb + (size_t)S_ * D_;
    for (int b = 0; b < B_; ++b) {
      gemm_f32_kernel<<<dim3(8, 32, 3), 256, 0, stream>>>(
          x, Wq, Wk, Wv, bq, bk, bv, Qb, Kb, Vb, perm, b, 0);
      attn_f32_kernel<<<256, 256, 0, stream>>>(Qb, Kb, Vb);
      gemm_f32_kernel<<<dim3(8, 32, 1), 256, 0, stream>>>(
          Qb, Wo, Wo, Wo, bo, bo, bo, out, out, out, perm, b, 1);
    }
  }
}